// Round 3
// baseline (957.981 us; speedup 1.0000x reference)
//
#include <hip/hip_runtime.h>

typedef __bf16 bf16;
typedef __bf16 bf16x8 __attribute__((ext_vector_type(8)));
typedef float f32x4 __attribute__((ext_vector_type(4)));

__device__ __forceinline__ void gld_lds16(const bf16* g, bf16* lds_base) {
    __builtin_amdgcn_global_load_lds(
        (const __attribute__((address_space(1))) void*)g,
        (__attribute__((address_space(3))) void*)lds_base, 16, 0, 0);
}

#define MFMA16(a, b, c) __builtin_amdgcn_mfma_f32_16x16x32_bf16((a), (b), (c), 0, 0, 0)

// ---------------------------------------------------------------------------
// Dtype detector: flag=0 if float tensors are bf16, 1 if fp32.
// ---------------------------------------------------------------------------
__global__ void detect_k(const unsigned* __restrict__ rnn, int* __restrict__ flag) {
    const int lane = threadIdx.x;  // 64 threads
    const unsigned w = rnn[lane];
    const int e = (w >> 7) & 0xFF;
    const bool good = (e >= 100 && e <= 130);
    const unsigned long long m = __ballot(good);
    if (lane == 0) *flag = (__popcll(m) >= 48) ? 0 : 1;
}

// ---------------------------------------------------------------------------
// Batched 64x64 tile transpose: in (B,R,C) [dtype per flag] -> out (B,C,R) bf16.
// ---------------------------------------------------------------------------
__global__ __launch_bounds__(256) void transpose_k(const void* __restrict__ in_,
                                                   bf16* __restrict__ out,
                                                   const int* __restrict__ flag,
                                                   int R, int C) {
    __shared__ __align__(16) bf16 t[64][72];
    const int dt = *flag;
    const long boff = (long)blockIdx.z * R * C;
    const int c0 = blockIdx.x * 64, r0 = blockIdx.y * 64;
    const int lr = threadIdx.x >> 2;
    const int lc = (threadIdx.x & 3) * 16;

    bf16x8 v0, v1;
    if (dt) {
        const float* src = (const float*)in_ + boff + (long)(r0 + lr) * C + c0 + lc;
        float4 f0 = ((const float4*)src)[0];
        float4 f1 = ((const float4*)src)[1];
        float4 f2 = ((const float4*)src)[2];
        float4 f3 = ((const float4*)src)[3];
        v0[0]=(bf16)f0.x; v0[1]=(bf16)f0.y; v0[2]=(bf16)f0.z; v0[3]=(bf16)f0.w;
        v0[4]=(bf16)f1.x; v0[5]=(bf16)f1.y; v0[6]=(bf16)f1.z; v0[7]=(bf16)f1.w;
        v1[0]=(bf16)f2.x; v1[1]=(bf16)f2.y; v1[2]=(bf16)f2.z; v1[3]=(bf16)f2.w;
        v1[4]=(bf16)f3.x; v1[5]=(bf16)f3.y; v1[6]=(bf16)f3.z; v1[7]=(bf16)f3.w;
    } else {
        const bf16* src = (const bf16*)in_ + boff + (long)(r0 + lr) * C + c0 + lc;
        v0 = ((const bf16x8*)src)[0];
        v1 = ((const bf16x8*)src)[1];
    }
    *(bf16x8*)(&t[lr][lc])     = v0;
    *(bf16x8*)(&t[lr][lc + 8]) = v1;
    __syncthreads();

    bf16 tmp[16];
#pragma unroll
    for (int k = 0; k < 16; ++k) tmp[k] = t[lc + k][lr];
    bf16* dst = out + boff + (long)(c0 + lr) * R + r0 + lc;
    *(float4*)(dst)     = *(float4*)(&tmp[0]);
    *(float4*)(dst + 8) = *(float4*)(&tmp[8]);
}

// ===========================================================================
// 256x256 8-wave 4-phase-per-K-tile GEMM core (bf16 inputs only, dt==0).
// BK=64, 512 threads, waves 2(M)x4(N). Wave output: rows qm*128+wm*64+m*16,
// cols qn*128+wn*32+n*16 (qm,qn in {0,1}: the M/N halves; m 0..3; n 0..1).
// LDS 128 KiB: A/B each 2buf x 2half x [128][64] bf16, XOR-swizzled chunks
// (elem(r,c) at r*64 + ((c>>3)^(r&7))*8 + (c&7); source pre-swizzled so
// global_load_lds' linear dst yields the swizzled layout; BANK_CONFLICT=0).
//
// Phase schedule per K-tile t (quadrants m0n0, m0n1, m1n0, m1n1; B frags
// persist in regs so LDS half-buffer last-reads are: A0,B0@p1, B1@p2, A1@p3):
//   p1: ds_read A0(8)+B0(4); stage Ah1[t+1],Bh1[t+1]; bar; lgkm0; MFMA; bar
//   p2: ds_read B1(4);       stage Ah0[t+2];          bar; lgkm0; MFMA; bar
//   p3: ds_read A1(8);                                bar; lgkm0; MFMA; bar
//   p4:                      stage Bh0[t+2]; MFMA; vmcnt(4); bar
// vmcnt(4) = loads issued after tile t+1's newest half (Ah0[t+2]+Bh0[t+2])
// -> all of tile t+1 landed, ~3 phases of cover, never drains to 0 mid-loop.
// Stage targets are always half-buffers whose last LDS read was >=1 closing
// barrier ago (audited above).
// ===========================================================================
__device__ __forceinline__ void kloop256(const bf16* __restrict__ A,
                                         const bf16* __restrict__ Bt,
                                         int K, int m0, int n0, bf16* L,
                                         int wid, int lane,
                                         f32x4 (&acc)[2][2][4][2]) {
    const int wm = wid >> 2, wn = wid & 3;
    const int quad = lane >> 4, l15 = lane & 15;
    const int nt = K >> 6;

    // staging addressing (pre-swizzled global source)
    const int sr = wid * 8 + (lane >> 3);
    const int sc = ((lane & 7) ^ ((lane >> 3) & 7)) * 8;
    const bf16* Ag = A + (long)(m0 + sr) * K + sc;
    const bf16* Bg = Bt + (long)(n0 + sr) * K + sc;
    const long K64 = (long)K * 64, K128 = (long)K * 128;
    bf16* const As = L;            // (buf*2+half)*8192
    bf16* const Bs = L + 32768;
    const int w512 = wid * 512;

    // fragment read bases
    const int arow = (wm * 64 + l15) * 64;
    const int brow = (wn * 32 + l15) * 64;
    const int swz0 = ((0 * 4 + quad) ^ (l15 & 7)) * 8;
    const int swz1 = ((1 * 4 + quad) ^ (l15 & 7)) * 8;

    // prologue: Ah0[0] Bh0[0] Ah1[0] Bh1[0] Ah0[1] Bh0[1]  (12 loads/thread)
    gld_lds16(Ag,              As + w512);
    gld_lds16(Ag + K64,        As + 4096 + w512);
    gld_lds16(Bg,              Bs + w512);
    gld_lds16(Bg + K64,        Bs + 4096 + w512);
    gld_lds16(Ag + K128,       As + 8192 + w512);
    gld_lds16(Ag + K128 + K64, As + 8192 + 4096 + w512);
    gld_lds16(Bg + K128,       Bs + 8192 + w512);
    gld_lds16(Bg + K128 + K64, Bs + 8192 + 4096 + w512);
    gld_lds16(Ag + 64,         As + 16384 + w512);
    gld_lds16(Ag + K64 + 64,   As + 16384 + 4096 + w512);
    gld_lds16(Bg + 64,         Bs + 16384 + w512);
    gld_lds16(Bg + K64 + 64,   Bs + 16384 + 4096 + w512);
    asm volatile("s_waitcnt vmcnt(4)" ::: "memory");
    __builtin_amdgcn_s_barrier();

    bf16x8 af[4][2], b0[2][2], b1[2][2];

    for (int t = 0; t < nt; ++t) {
        const int buf = t & 1, nbuf = buf ^ 1;
        bf16* A0 = As + (buf * 2 + 0) * 8192;
        bf16* A1 = As + (buf * 2 + 1) * 8192;
        bf16* B0 = Bs + (buf * 2 + 0) * 8192;
        bf16* B1 = Bs + (buf * 2 + 1) * 8192;
        const long ko1 = (long)(t + 1) * 64;
        const long ko2 = (long)(t + 2) * 64;

        // ---- phase 1: Q(m0,n0); stage Ah1[t+1], Bh1[t+1]
#pragma unroll
        for (int m = 0; m < 4; ++m) {
            af[m][0] = *(const bf16x8*)(A0 + arow + m * 1024 + swz0);
            af[m][1] = *(const bf16x8*)(A0 + arow + m * 1024 + swz1);
        }
#pragma unroll
        for (int n = 0; n < 2; ++n) {
            b0[n][0] = *(const bf16x8*)(B0 + brow + n * 1024 + swz0);
            b0[n][1] = *(const bf16x8*)(B0 + brow + n * 1024 + swz1);
        }
        if (t + 1 < nt) {
            gld_lds16(Ag + K128 + ko1,       As + (nbuf * 2 + 1) * 8192 + w512);
            gld_lds16(Ag + K128 + K64 + ko1, As + (nbuf * 2 + 1) * 8192 + 4096 + w512);
            gld_lds16(Bg + K128 + ko1,       Bs + (nbuf * 2 + 1) * 8192 + w512);
            gld_lds16(Bg + K128 + K64 + ko1, Bs + (nbuf * 2 + 1) * 8192 + 4096 + w512);
        }
        __builtin_amdgcn_s_barrier();
        asm volatile("s_waitcnt lgkmcnt(0)" ::: "memory");
        __builtin_amdgcn_sched_barrier(0);
        __builtin_amdgcn_s_setprio(1);
#pragma unroll
        for (int m = 0; m < 4; ++m)
#pragma unroll
            for (int n = 0; n < 2; ++n) {
                acc[0][0][m][n] = MFMA16(af[m][0], b0[n][0], acc[0][0][m][n]);
                acc[0][0][m][n] = MFMA16(af[m][1], b0[n][1], acc[0][0][m][n]);
            }
        __builtin_amdgcn_s_setprio(0);
        __builtin_amdgcn_sched_barrier(0);
        __builtin_amdgcn_s_barrier();

        // ---- phase 2: Q(m0,n1); stage Ah0[t+2]
#pragma unroll
        for (int n = 0; n < 2; ++n) {
            b1[n][0] = *(const bf16x8*)(B1 + brow + n * 1024 + swz0);
            b1[n][1] = *(const bf16x8*)(B1 + brow + n * 1024 + swz1);
        }
        if (t + 2 < nt) {
            gld_lds16(Ag + ko2,       A0 + w512);
            gld_lds16(Ag + K64 + ko2, A0 + 4096 + w512);
        }
        __builtin_amdgcn_s_barrier();
        asm volatile("s_waitcnt lgkmcnt(0)" ::: "memory");
        __builtin_amdgcn_sched_barrier(0);
        __builtin_amdgcn_s_setprio(1);
#pragma unroll
        for (int m = 0; m < 4; ++m)
#pragma unroll
            for (int n = 0; n < 2; ++n) {
                acc[0][1][m][n] = MFMA16(af[m][0], b1[n][0], acc[0][1][m][n]);
                acc[0][1][m][n] = MFMA16(af[m][1], b1[n][1], acc[0][1][m][n]);
            }
        __builtin_amdgcn_s_setprio(0);
        __builtin_amdgcn_sched_barrier(0);
        __builtin_amdgcn_s_barrier();

        // ---- phase 3: Q(m1,n0); no stage
#pragma unroll
        for (int m = 0; m < 4; ++m) {
            af[m][0] = *(const bf16x8*)(A1 + arow + m * 1024 + swz0);
            af[m][1] = *(const bf16x8*)(A1 + arow + m * 1024 + swz1);
        }
        __builtin_amdgcn_s_barrier();
        asm volatile("s_waitcnt lgkmcnt(0)" ::: "memory");
        __builtin_amdgcn_sched_barrier(0);
        __builtin_amdgcn_s_setprio(1);
#pragma unroll
        for (int m = 0; m < 4; ++m)
#pragma unroll
            for (int n = 0; n < 2; ++n) {
                acc[1][0][m][n] = MFMA16(af[m][0], b0[n][0], acc[1][0][m][n]);
                acc[1][0][m][n] = MFMA16(af[m][1], b0[n][1], acc[1][0][m][n]);
            }
        __builtin_amdgcn_s_setprio(0);
        __builtin_amdgcn_sched_barrier(0);
        __builtin_amdgcn_s_barrier();

        // ---- phase 4: Q(m1,n1); stage Bh0[t+2]; counted vmcnt; publish
        if (t + 2 < nt) {
            gld_lds16(Bg + ko2,       B0 + w512);
            gld_lds16(Bg + K64 + ko2, B0 + 4096 + w512);
        }
        __builtin_amdgcn_s_setprio(1);
#pragma unroll
        for (int m = 0; m < 4; ++m)
#pragma unroll
            for (int n = 0; n < 2; ++n) {
                acc[1][1][m][n] = MFMA16(af[m][0], b1[n][0], acc[1][1][m][n]);
                acc[1][1][m][n] = MFMA16(af[m][1], b1[n][1], acc[1][1][m][n]);
            }
        __builtin_amdgcn_s_setprio(0);
        __builtin_amdgcn_sched_barrier(0);
        if (t + 2 < nt) {
            asm volatile("s_waitcnt vmcnt(4)" ::: "memory");
        } else if (t + 1 < nt) {
            asm volatile("s_waitcnt vmcnt(0)" ::: "memory");
        }
        __builtin_amdgcn_s_barrier();
    }
}

// grid (8, y[, z]); 8*y blocks per slice, must be multiple of 32, y % 4 == 0.
// lin%8 = XCD; per-XCD contiguous mb chunk for A-panel L2 reuse.
__device__ __forceinline__ void tile256_coords(int& m0, int& n0) {
    const int lin = blockIdx.y * 8 + blockIdx.x;
    const int x = lin & 7, j = lin >> 3;
    const int mbPerX = (int)(gridDim.x * gridDim.y) >> 5;
    m0 = (x * mbPerX + (j >> 2)) * 256;
    n0 = (j & 3) * 256;
}

// ---------------------------------------------------------------------------
// 256^2 front GEMM (bf16 path): C = bf16(relu(A @ Bt^T + bias)).
// ---------------------------------------------------------------------------
__global__ __launch_bounds__(512, 2) void gemm256_front(
        const void* __restrict__ A_, const bf16* __restrict__ Bt,
        const void* __restrict__ bias_, bf16* __restrict__ C,
        const int* __restrict__ flag, int M, int N, int K) {
    if (*flag != 0) return;   // fp32 inputs handled by the 128^2 kernels
    __shared__ __align__(16) bf16 L[65536];
    const int tid = threadIdx.x, lane = tid & 63, wid = tid >> 6;
    int m0, n0;
    tile256_coords(m0, n0);

    f32x4 acc[2][2][4][2];
#pragma unroll
    for (int a = 0; a < 2; ++a)
#pragma unroll
        for (int b = 0; b < 2; ++b)
#pragma unroll
            for (int m = 0; m < 4; ++m)
#pragma unroll
                for (int n = 0; n < 2; ++n) acc[a][b][m][n] = (f32x4){0.f,0.f,0.f,0.f};

    kloop256((const bf16*)A_, Bt, K, m0, n0, L, wid, lane, acc);

    const bf16* bias = (const bf16*)bias_;
    const int wm = wid >> 2, wn = wid & 3;
    const int quad = lane >> 4, l15 = lane & 15;
#pragma unroll
    for (int qn = 0; qn < 2; ++qn)
#pragma unroll
        for (int n = 0; n < 2; ++n) {
            const int colg = n0 + qn * 128 + wn * 32 + n * 16 + l15;
            const float bj = (float)bias[colg];
#pragma unroll
            for (int qm = 0; qm < 2; ++qm)
#pragma unroll
                for (int m = 0; m < 4; ++m) {
                    const int rowb = m0 + qm * 128 + wm * 64 + m * 16 + quad * 4;
#pragma unroll
                    for (int r = 0; r < 4; ++r) {
                        float v = acc[qm][qn][m][n][r] + bj;
                        v = v > 0.f ? v : 0.f;
                        C[(long)(rowb + r) * N + colg] = (bf16)v;
                    }
                }
        }
}

// ---------------------------------------------------------------------------
// Expert descriptors (shared by 128^2 fallback and 256^2 kernels)
// ---------------------------------------------------------------------------
struct ExpDescs {
    const void* A[7];
    const bf16* Bt[7];
    const void* biasB[7];
    const void* w2B[7];
    float* S[7];
    long biasEoff[7];
    long w2Eoff[7];
    int K[7];
    int adt[7];   // 1: A has input dtype (per flag); 0: A is ws bf16
};

// ---------------------------------------------------------------------------
// 256^2 expert GEMM (bf16 path) with fused layer-2 epilogue.
// grid (8, 4, 7).
// ---------------------------------------------------------------------------
__global__ __launch_bounds__(512, 2) void gemm256_expert(ExpDescs d,
                                                         const int* __restrict__ flag) {
    if (*flag != 0) return;
    __shared__ __align__(16) bf16 L[65536];
    const int z = blockIdx.z;
    const int K = d.K[z];
    const int tid = threadIdx.x, lane = tid & 63, wid = tid >> 6;
    int m0, n0;
    tile256_coords(m0, n0);

    f32x4 acc[2][2][4][2];
#pragma unroll
    for (int a = 0; a < 2; ++a)
#pragma unroll
        for (int b = 0; b < 2; ++b)
#pragma unroll
            for (int m = 0; m < 4; ++m)
#pragma unroll
                for (int n = 0; n < 2; ++n) acc[a][b][m][n] = (f32x4){0.f,0.f,0.f,0.f};

    kloop256((const bf16*)d.A[z], d.Bt[z], K, m0, n0, L, wid, lane, acc);

    const bf16* bias_b = (const bf16*)d.biasB[z] + d.biasEoff[z];
    const bf16* w2_b   = (const bf16*)d.w2B[z] + d.w2Eoff[z];
    float* S = d.S[z];
    const int wm = wid >> 2, wn = wid & 3;
    const int quad = lane >> 4, l15 = lane & 15;

    float bj[2][2], w2f[2][2][2];
#pragma unroll
    for (int qn = 0; qn < 2; ++qn)
#pragma unroll
        for (int n = 0; n < 2; ++n) {
            const int colg = n0 + qn * 128 + wn * 32 + n * 16 + l15;
            bj[qn][n] = (float)bias_b[colg];
            w2f[qn][n][0] = (float)w2_b[colg * 2 + 0];
            w2f[qn][n][1] = (float)w2_b[colg * 2 + 1];
        }
#pragma unroll
    for (int qm = 0; qm < 2; ++qm)
#pragma unroll
        for (int m = 0; m < 4; ++m)
#pragma unroll
            for (int r = 0; r < 4; ++r) {
                float s0 = 0.f, s1 = 0.f;
#pragma unroll
                for (int qn = 0; qn < 2; ++qn)
#pragma unroll
                    for (int n = 0; n < 2; ++n) {
                        float h = acc[qm][qn][m][n][r] + bj[qn][n];
                        h = h > 0.f ? h : 0.f;
                        s0 += h * w2f[qn][n][0];
                        s1 += h * w2f[qn][n][1];
                    }
#pragma unroll
                for (int msk = 1; msk < 16; msk <<= 1) {
                    s0 += __shfl_xor(s0, msk);
                    s1 += __shfl_xor(s1, msk);
                }
                if (l15 == 0) {
                    const int rowg = m0 + qm * 128 + wm * 64 + m * 16 + quad * 4 + r;
                    atomicAdd(&S[rowg * 2 + 0], s0);
                    atomicAdd(&S[rowg * 2 + 1], s1);
                }
            }
}

// ===========================================================================
// 128^2 kernels: fp32-input (dt==1) fallback path. Early-return when dt==0.
// ===========================================================================
__device__ __forceinline__ void mfma_tile(const bf16* As, const bf16* Bs,
                                          int wm, int wn, int quad, int l15,
                                          f32x4 acc[4][4]) {
#pragma unroll
    for (int kk = 0; kk < 2; ++kk) {
        bf16x8 af[4], bff[4];
        const int kc = kk * 4 + quad;
#pragma unroll
        for (int i = 0; i < 4; ++i) {
            const int m = wm * 64 + i * 16 + l15;
            af[i] = *(const bf16x8*)(As + m * 64 + (kc ^ (m & 7)) * 8);
            const int n = wn * 64 + i * 16 + l15;
            bff[i] = *(const bf16x8*)(Bs + n * 64 + (kc ^ (n & 7)) * 8);
        }
#pragma unroll
        for (int i = 0; i < 4; ++i)
#pragma unroll
            for (int j = 0; j < 4; ++j)
                acc[i][j] = __builtin_amdgcn_mfma_f32_16x16x32_bf16(
                    af[i], bff[j], acc[i][j], 0, 0, 0);
    }
}

__device__ __forceinline__ void stageAB(const bf16* a, const bf16* b, int K,
                                        bf16* Asb, bf16* Bsb, int lbase) {
#pragma unroll
    for (int r = 0; r < 4; ++r) {
        gld_lds16(a + (long)(r * 32) * K, Asb + r * 2048 + lbase);
        gld_lds16(b + (long)(r * 32) * K, Bsb + r * 2048 + lbase);
    }
}

__device__ __forceinline__ void stageB(const bf16* b, int K, bf16* Bsb, int lbase) {
#pragma unroll
    for (int r = 0; r < 4; ++r)
        gld_lds16(b + (long)(r * 32) * K, Bsb + r * 2048 + lbase);
}

__device__ __forceinline__ void issueA_f32(const char* Ag4, int K, int k0,
                                           float4 fa[8]) {
#pragma unroll
    for (int r = 0; r < 4; ++r) {
        const float4* pa = (const float4*)(Ag4 + ((long)(r * 32) * K + k0) * 4);
        fa[2 * r]     = pa[0];
        fa[2 * r + 1] = pa[1];
    }
}

__device__ __forceinline__ void writeA_cvt(bf16* Asb, const float4 fa[8], int ldst) {
#pragma unroll
    for (int r = 0; r < 4; ++r) {
        const float4 f0 = fa[2 * r], f1 = fa[2 * r + 1];
        bf16x8 v;
        v[0]=(bf16)f0.x; v[1]=(bf16)f0.y; v[2]=(bf16)f0.z; v[3]=(bf16)f0.w;
        v[4]=(bf16)f1.x; v[5]=(bf16)f1.y; v[6]=(bf16)f1.z; v[7]=(bf16)f1.w;
        *(bf16x8*)(Asb + r * 2048 + ldst) = v;
    }
}

__device__ __forceinline__ void kloop_bf16(const bf16* Agb, const bf16* Bg, int K,
                                           bf16* As, bf16* Bs, int lbase,
                                           int wm, int wn, int quad, int l15,
                                           f32x4 acc[4][4]) {
    const int nt = K >> 6;
    stageAB(Agb, Bg, K, As, Bs, lbase);
    for (int t = 0; t < nt; ++t) {
        const int cur = (t & 1) * 8192;
        if (t + 1 < nt) {
            const int nxt = ((t + 1) & 1) * 8192;
            stageAB(Agb + ((t + 1) << 6), Bg + ((t + 1) << 6), K,
                    As + nxt, Bs + nxt, lbase);
            asm volatile("s_waitcnt vmcnt(8)" ::: "memory");
        } else {
            asm volatile("s_waitcnt vmcnt(0)" ::: "memory");
        }
        __builtin_amdgcn_s_barrier();
        __builtin_amdgcn_sched_barrier(0);
        mfma_tile(As + cur, Bs + cur, wm, wn, quad, l15, acc);
        __builtin_amdgcn_sched_barrier(0);
        __builtin_amdgcn_s_barrier();
    }
}

__global__ __launch_bounds__(256, 2) void gemm_front(const void* __restrict__ A_,
                                                     const bf16* __restrict__ Bt,
                                                     const void* __restrict__ bias_,
                                                     bf16* __restrict__ C,
                                                     const int* __restrict__ flag,
                                                     int M, int N, int K) {
    const int dt = *flag;
    if (dt == 0) return;   // bf16 path handled by gemm256_front
    __shared__ __align__(16) bf16 As[2][128 * 64];
    __shared__ __align__(16) bf16 Bs[2][128 * 64];

    const int tid = threadIdx.x, lane = tid & 63, wid = tid >> 6;
    const int wm = wid & 1, wn = wid >> 1;

    const int lin = blockIdx.y * 8 + blockIdx.x;
    const int m0 = ((lin >> 6) * 8 + (lin & 7)) * 128;
    const int n0 = ((lin >> 3) & 7) * 128;

    const int srow = wid * 8 + (lane >> 3);
    const int scol = ((lane & 7) ^ (srow & 7)) * 8;
    const bf16* Bg = Bt + (long)(n0 + srow) * K + scol;
    const int ldst = wid * 512 + lane * 8;
    const int lbase = wid * 512;

    f32x4 acc[4][4];
#pragma unroll
    for (int i = 0; i < 4; ++i)
#pragma unroll
        for (int j = 0; j < 4; ++j) acc[i][j] = (f32x4){0.f, 0.f, 0.f, 0.f};

    const int quad = lane >> 4, l15 = lane & 15;
    const int nt = K >> 6;

    {  // fp32 A: reg-stage A (issue-early / convert-late), async B
        const char* Ag4 = (const char*)A_ + ((long)(m0 + srow) * K + scol) * 4;
        float4 fa[8];
        issueA_f32(Ag4, K, 0, fa);
        stageB(Bg, K, Bs[0], lbase);
        writeA_cvt(As[0], fa, ldst);
        __syncthreads();
        int t = 0;
        for (; t < nt - 2; t += 2) {
            issueA_f32(Ag4, K, (t + 1) << 6, fa);
            stageB(Bg + ((t + 1) << 6), K, Bs[1], lbase);
            mfma_tile(As[0], Bs[0], wm, wn, quad, l15, acc);
            writeA_cvt(As[1], fa, ldst);
            __syncthreads();
            issueA_f32(Ag4, K, (t + 2) << 6, fa);
            stageB(Bg + ((t + 2) << 6), K, Bs[0], lbase);
            mfma_tile(As[1], Bs[1], wm, wn, quad, l15, acc);
            writeA_cvt(As[0], fa, ldst);
            __syncthreads();
        }
        issueA_f32(Ag4, K, (nt - 1) << 6, fa);
        stageB(Bg + ((nt - 1) << 6), K, Bs[1], lbase);
        mfma_tile(As[0], Bs[0], wm, wn, quad, l15, acc);
        writeA_cvt(As[1], fa, ldst);
        __syncthreads();
        mfma_tile(As[1], Bs[1], wm, wn, quad, l15, acc);
    }

#pragma unroll
    for (int j = 0; j < 4; ++j) {
        const int colg = n0 + wn * 64 + j * 16 + l15;
        const float bj = ((const float*)bias_)[colg];
#pragma unroll
        for (int i = 0; i < 4; ++i) {
            const int rowb = m0 + wm * 64 + i * 16 + quad * 4;
#pragma unroll
            for (int r = 0; r < 4; ++r) {
                float v = acc[i][j][r] + bj;
                v = v > 0.f ? v : 0.f;
                C[(long)(rowb + r) * N + colg] = (bf16)v;
            }
        }
    }
}

__global__ __launch_bounds__(256, 2) void gemm_expert(ExpDescs d,
                                                      const int* __restrict__ flag) {
    const int dt = *flag;
    if (dt == 0) return;   // bf16 path handled by gemm256_expert
    __shared__ __align__(16) bf16 As[2][128 * 64];
    __shared__ __align__(16) bf16 Bs[2][128 * 64];

    const int z = blockIdx.z;
    const int adt = d.adt[z];
    const int K = d.K[z];
    const void* A_ = d.A[z];
    const bf16* Bt = d.Bt[z];

    const int tid = threadIdx.x, lane = tid & 63, wid = tid >> 6;
    const int wm = wid & 1, wn = wid >> 1;

    const int lin = blockIdx.y * 8 + blockIdx.x;
    const int m0 = ((lin >> 6) * 8 + (lin & 7)) * 128;
    const int n0 = ((lin >> 3) & 7) * 128;

    const int srow = wid * 8 + (lane >> 3);
    const int scol = ((lane & 7) ^ (srow & 7)) * 8;
    const bf16* Bg = Bt + (long)(n0 + srow) * K + scol;
    const int ldst = wid * 512 + lane * 8;
    const int lbase = wid * 512;

    f32x4 acc[4][4];
#pragma unroll
    for (int i = 0; i < 4; ++i)
#pragma unroll
        for (int j = 0; j < 4; ++j) acc[i][j] = (f32x4){0.f, 0.f, 0.f, 0.f};

    const int quad = lane >> 4, l15 = lane & 15;
    const int nt = K >> 6;

    if (adt) {  // fp32 A
        const char* Ag4 = (const char*)A_ + ((long)(m0 + srow) * K + scol) * 4;
        float4 fa[8];
        issueA_f32(Ag4, K, 0, fa);
        stageB(Bg, K, Bs[0], lbase);
        writeA_cvt(As[0], fa, ldst);
        __syncthreads();
        int t = 0;
        for (; t < nt - 2; t += 2) {
            issueA_f32(Ag4, K, (t + 1) << 6, fa);
            stageB(Bg + ((t + 1) << 6), K, Bs[1], lbase);
            mfma_tile(As[0], Bs[0], wm, wn, quad, l15, acc);
            writeA_cvt(As[1], fa, ldst);
            __syncthreads();
            issueA_f32(Ag4, K, (t + 2) << 6, fa);
            stageB(Bg + ((t + 2) << 6), K, Bs[0], lbase);
            mfma_tile(As[1], Bs[1], wm, wn, quad, l15, acc);
            writeA_cvt(As[0], fa, ldst);
            __syncthreads();
        }
        issueA_f32(Ag4, K, (nt - 1) << 6, fa);
        stageB(Bg + ((nt - 1) << 6), K, Bs[1], lbase);
        mfma_tile(As[0], Bs[0], wm, wn, quad, l15, acc);
        writeA_cvt(As[1], fa, ldst);
        __syncthreads();
        mfma_tile(As[1], Bs[1], wm, wn, quad, l15, acc);
    } else {    // ws bf16 A (hc/xd when dt==1)
        const bf16* Agb = (const bf16*)A_ + (long)(m0 + srow) * K + scol;
        kloop_bf16(Agb, Bg, K, As[0], Bs[0], lbase, wm, wn, quad, l15, acc);
    }

    // fused layer-2 epilogue (dt==1: fp32 bias/w2)
    const char* bias_b = (const char*)d.biasB[z] + d.biasEoff[z] * 4;
    const char* w2_b   = (const char*)d.w2B[z] + d.w2Eoff[z] * 4;
    float* S = d.S[z];

    float bj[4], w2f[4][2];
#pragma unroll
    for (int j = 0; j < 4; ++j) {
        const int colg = n0 + wn * 64 + j * 16 + l15;
        bj[j] = ((const float*)bias_b)[colg];
        w2f[j][0] = ((const float*)w2_b)[colg * 2 + 0];
        w2f[j][1] = ((const float*)w2_b)[colg * 2 + 1];
    }
#pragma unroll
    for (int i = 0; i < 4; ++i) {
#pragma unroll
        for (int r = 0; r < 4; ++r) {
            float s0 = 0.f, s1 = 0.f;
#pragma unroll
            for (int j = 0; j < 4; ++j) {
                float h = acc[i][j][r] + bj[j];
                h = h > 0.f ? h : 0.f;
                s0 += h * w2f[j][0];
                s1 += h * w2f[j][1];
            }
#pragma unroll
            for (int msk = 1; msk < 16; msk <<= 1) {
                s0 += __shfl_xor(s0, msk);
                s1 += __shfl_xor(s1, msk);
            }
            if (l15 == 0) {
                const int rowg = m0 + wm * 64 + i * 16 + quad * 4 + r;
                atomicAdd(&S[rowg * 2 + 0], s0);
                atomicAdd(&S[rowg * 2 + 1], s1);
            }
        }
    }
}

// ---------------------------------------------------------------------------
// x_dist[n,0:1024] = hd[3n]*hd[3n+1]; x_dist[n,1024:2048] = hd[3n+1]*hd[3n+2]
// ---------------------------------------------------------------------------
__global__ __launch_bounds__(256) void pairprod_k(const bf16* __restrict__ hd,
                                                  bf16* __restrict__ xd) {
    const int idx = blockIdx.x * 256 + threadIdx.x;  // 524288 total
    const int n = idx >> 8;
    const int c8 = (idx & 255) << 3;
    const bf16* p;
    if (c8 < 1024) p = hd + (long)(3 * n) * 1024 + c8;
    else           p = hd + (long)(3 * n + 1) * 1024 + (c8 - 1024);
    const bf16* q = p + 1024;
    bf16x8 a = *(const bf16x8*)p, b = *(const bf16x8*)q;
    bf16x8 o;
#pragma unroll
    for (int k = 0; k < 8; ++k) o[k] = (bf16)((float)a[k] * (float)b[k]);
    *(bf16x8*)(xd + (long)n * 2048 + c8) = o;
}

// ---------------------------------------------------------------------------
// out[(g*2048+n)*2+o] = S[g][eid][n][o] + b2[g][eid][o], dtype per flag.
// ---------------------------------------------------------------------------
__global__ __launch_bounds__(256) void finalize_k(const float* __restrict__ S,
        const int* __restrict__ rnn_eid, const int* __restrict__ room_eid,
        const int* __restrict__ dist_eid, const void* __restrict__ b2_rnn,
        const void* __restrict__ b2_room, const void* __restrict__ b2_dist,
        const int* __restrict__ flag, void* __restrict__ out) {
    const int idx = blockIdx.x * 256 + threadIdx.x;
    if (idx >= 12288) return;
    const int dt = *flag;
    const int o = idx & 1;
    const int row = idx >> 1;
    const int g = row >> 11;
    const int n = row & 2047;
    float v;
    if (g == 0) {
        int e = rnn_eid[n]; e = e < 0 ? 0 : (e > 2 ? 2 : e);
        v = S[e * 4096 + n * 2 + o] +
            (dt ? ((const float*)b2_rnn)[e * 2 + o]
                : (float)((const bf16*)b2_rnn)[e * 2 + o]);
    } else if (g == 1) {
        int e = room_eid[n]; e = e < 0 ? 0 : (e > 1 ? 1 : e);
        v = S[12288 + e * 4096 + n * 2 + o] +
            (dt ? ((const float*)b2_room)[e * 2 + o]
                : (float)((const bf16*)b2_room)[e * 2 + o]);
    } else {
        int e = dist_eid[n]; e = e < 0 ? 0 : (e > 1 ? 1 : e);
        v = S[20480 + e * 4096 + n * 2 + o] +
            (dt ? ((const float*)b2_dist)[e * 2 + o]
                : (float)((const bf16*)b2_dist)[e * 2 + o]);
    }
    if (dt) ((float*)out)[idx] = v;
    else    ((bf16*)out)[idx] = (bf16)v;
}

extern "C" void kernel_launch(void* const* d_in, const int* in_sizes, int n_in,
                              void* d_out, int out_size, void* d_ws, size_t ws_size,
                              hipStream_t stream) {
    const void* rnn_feats = d_in[0];
    const void* cube      = d_in[1];
    const void* ego       = d_in[2];
    const int* rnn_eid    = (const int*)d_in[3];
    const int* room_eid   = (const int*)d_in[4];
    const int* dist_eid   = (const int*)d_in[5];
    const void* Wc        = d_in[6];
    const void* bc        = d_in[7];
    const void* Wd        = d_in[8];
    const void* bd        = d_in[9];
    const void* W1_rnn    = d_in[10];
    const void* b1_rnn    = d_in[11];
    const void* W2_rnn    = d_in[12];
    const void* b2_rnn    = d_in[13];
    const void* W1_room   = d_in[14];
    const void* b1_room   = d_in[15];
    const void* W2_room   = d_in[16];
    const void* b2_room   = d_in[17];
    const void* W1_dist   = d_in[18];
    const void* b1_dist   = d_in[19];
    const void* W2_dist   = d_in[20];
    const void* b2_dist   = d_in[21];

    char* ws = (char*)d_ws;
    float* S     = (float*)ws;                    // 28672 fp32 = 114688 B
    int* flag    = (int*)(ws + 114688);           // 4 B (pad to 256)
    bf16* WcT    = (bf16*)(ws + 114944);          // 1024x3200
    bf16* WdT    = (bf16*)(ws + 6668544);         // 1024x3712
    bf16* WrnnT  = (bf16*)(ws + 14270720);        // 3x1024x1024
    bf16* WroomT = (bf16*)(ws + 20562176);        // 2x1024x8192
    bf16* WdistT = (bf16*)(ws + 54116608);        // 2x1024x2048
    bf16* hc     = (bf16*)(ws + 62505216);        // 16384x1024
    bf16* hd     = (bf16*)(ws + 96059648);        // 6144x1024
    bf16* xd     = (bf16*)(ws + 108642560);       // 2048x2048

    detect_k<<<1, 64, 0, stream>>>((const unsigned*)rnn_feats, flag);
    hipMemsetAsync(S, 0, 114688, stream);

    transpose_k<<<dim3(16, 50, 1),  256, 0, stream>>>(Wc,      WcT,    flag, 3200, 1024);
    transpose_k<<<dim3(16, 58, 1),  256, 0, stream>>>(Wd,      WdT,    flag, 3712, 1024);
    transpose_k<<<dim3(16, 16, 3),  256, 0, stream>>>(W1_rnn,  WrnnT,  flag, 1024, 1024);
    transpose_k<<<dim3(16, 128, 2), 256, 0, stream>>>(W1_room, WroomT, flag, 8192, 1024);
    transpose_k<<<dim3(16, 32, 2),  256, 0, stream>>>(W1_dist, WdistT, flag, 2048, 1024);

    // hc = relu(cube @ Wc + bc) (16384x1024); hd = relu(ego @ Wd + bd) (6144x1024)
    gemm256_front<<<dim3(8, 32), 512, 0, stream>>>(cube, WcT, bc, hc, flag,
                                                   16384, 1024, 3200);
    gemm_front<<<dim3(8, 128), 256, 0, stream>>>(cube, WcT, bc, hc, flag,
                                                 16384, 1024, 3200);
    gemm256_front<<<dim3(8, 12), 512, 0, stream>>>(ego, WdT, bd, hd, flag,
                                                   6144, 1024, 3712);
    gemm_front<<<dim3(8, 48), 256, 0, stream>>>(ego, WdT, bd, hd, flag,
                                                6144, 1024, 3712);
    pairprod_k<<<2048, 256, 0, stream>>>(hd, xd);

    // all 7 expert GEMMs (layer1 + fused layer2 -> S); room (K=8192) first.
    ExpDescs D;
    for (int e = 0; e < 2; ++e) {
        const int z = e;
        D.A[z] = hc;                   D.Bt[z] = WroomT + (long)e * 1024 * 8192;
        D.biasB[z] = b1_room;          D.biasEoff[z] = (long)e * 1024;
        D.w2B[z] = W2_room;            D.w2Eoff[z] = (long)e * 2048;
        D.S[z] = S + 12288 + e * 4096; D.K[z] = 8192;  D.adt[z] = 0;
    }
    for (int e = 0; e < 2; ++e) {
        const int z = 2 + e;
        D.A[z] = xd;                   D.Bt[z] = WdistT + (long)e * 1024 * 2048;
        D.biasB[z] = b1_dist;          D.biasEoff[z] = (long)e * 1024;
        D.w2B[z] = W2_dist;            D.w2Eoff[z] = (long)e * 2048;
        D.S[z] = S + 20480 + e * 4096; D.K[z] = 2048;  D.adt[z] = 0;
    }
    for (int e = 0; e < 3; ++e) {
        const int z = 4 + e;
        D.A[z] = rnn_feats;            D.Bt[z] = WrnnT + (long)e * 1024 * 1024;
        D.biasB[z] = b1_rnn;           D.biasEoff[z] = (long)e * 1024;
        D.w2B[z] = W2_rnn;             D.w2Eoff[z] = (long)e * 2048;
        D.S[z] = S + e * 4096;         D.K[z] = 1024;  D.adt[z] = 1;
    }
    gemm256_expert<<<dim3(8, 4, 7), 512, 0, stream>>>(D, flag);
    gemm_expert<<<dim3(8, 16, 7), 256, 0, stream>>>(D, flag);

    finalize_k<<<48, 256, 0, stream>>>(S, rnn_eid, room_eid, dist_eid,
                                       b2_rnn, b2_room, b2_dist, flag, d_out);
}

// Round 4
// 895.852 us; speedup vs baseline: 1.0694x; 1.0694x over previous
//
#include <hip/hip_runtime.h>

typedef __bf16 bf16;
typedef __bf16 bf16x8 __attribute__((ext_vector_type(8)));
typedef float f32x4 __attribute__((ext_vector_type(4)));

__device__ __forceinline__ void gld_lds16(const bf16* g, bf16* lds_base) {
    __builtin_amdgcn_global_load_lds(
        (const __attribute__((address_space(1))) void*)g,
        (__attribute__((address_space(3))) void*)lds_base, 16, 0, 0);
}

// ---------------------------------------------------------------------------
// Dtype detector: flag=0 if float tensors are bf16, 1 if fp32.
// (Measured r3: flag==1 on the bench -- inputs are fp32.)
// ---------------------------------------------------------------------------
__global__ void detect_k(const unsigned* __restrict__ rnn, int* __restrict__ flag) {
    const int lane = threadIdx.x;  // 64 threads
    const unsigned w = rnn[lane];
    const int e = (w >> 7) & 0xFF;
    const bool good = (e >= 100 && e <= 130);
    const unsigned long long m = __ballot(good);
    if (lane == 0) *flag = (__popcll(m) >= 48) ? 0 : 1;
}

// ---------------------------------------------------------------------------
// fp32 -> bf16 cast of the three activation tensors (only when dt==1 and the
// workspace tier allows). Pure-BW: 8 elems/lane, grid-stride.
// ---------------------------------------------------------------------------
__device__ __forceinline__ void cvt8(const float* __restrict__ s,
                                     bf16* __restrict__ d, long i8) {
    const float4* p = (const float4*)(s + i8 * 8);
    const float4 f0 = p[0], f1 = p[1];
    bf16x8 v;
    v[0]=(bf16)f0.x; v[1]=(bf16)f0.y; v[2]=(bf16)f0.z; v[3]=(bf16)f0.w;
    v[4]=(bf16)f1.x; v[5]=(bf16)f1.y; v[6]=(bf16)f1.z; v[7]=(bf16)f1.w;
    *(bf16x8*)(d + i8 * 8) = v;
}

__global__ __launch_bounds__(256) void cast_k(
        const float* __restrict__ cube, const float* __restrict__ ego,
        const float* __restrict__ rnn, bf16* __restrict__ cubeB,
        bf16* __restrict__ egoB, bf16* __restrict__ rnnB,
        int cc, int ce, int cr, const int* __restrict__ flag) {
    if (*flag == 0) return;   // inputs already bf16
    const long tid = (long)blockIdx.x * 256 + threadIdx.x;
    const long stride = (long)gridDim.x * 256;
    if (cc) for (long i = tid; i < 6553600; i += stride) cvt8(cube, cubeB, i);
    if (ce) for (long i = tid; i < 2850816; i += stride) cvt8(ego, egoB, i);
    if (cr) for (long i = tid; i < 262144;  i += stride) cvt8(rnn, rnnB, i);
}

// ---------------------------------------------------------------------------
// Batched 64x64 tile transpose: in (B,R,C) [dtype per flag] -> out (B,C,R) bf16.
// ---------------------------------------------------------------------------
__global__ __launch_bounds__(256) void transpose_k(const void* __restrict__ in_,
                                                   bf16* __restrict__ out,
                                                   const int* __restrict__ flag,
                                                   int R, int C) {
    __shared__ __align__(16) bf16 t[64][72];
    const int dt = *flag;
    const long boff = (long)blockIdx.z * R * C;
    const int c0 = blockIdx.x * 64, r0 = blockIdx.y * 64;
    const int lr = threadIdx.x >> 2;
    const int lc = (threadIdx.x & 3) * 16;

    bf16x8 v0, v1;
    if (dt) {
        const float* src = (const float*)in_ + boff + (long)(r0 + lr) * C + c0 + lc;
        float4 f0 = ((const float4*)src)[0];
        float4 f1 = ((const float4*)src)[1];
        float4 f2 = ((const float4*)src)[2];
        float4 f3 = ((const float4*)src)[3];
        v0[0]=(bf16)f0.x; v0[1]=(bf16)f0.y; v0[2]=(bf16)f0.z; v0[3]=(bf16)f0.w;
        v0[4]=(bf16)f1.x; v0[5]=(bf16)f1.y; v0[6]=(bf16)f1.z; v0[7]=(bf16)f1.w;
        v1[0]=(bf16)f2.x; v1[1]=(bf16)f2.y; v1[2]=(bf16)f2.z; v1[3]=(bf16)f2.w;
        v1[4]=(bf16)f3.x; v1[5]=(bf16)f3.y; v1[6]=(bf16)f3.z; v1[7]=(bf16)f3.w;
    } else {
        const bf16* src = (const bf16*)in_ + boff + (long)(r0 + lr) * C + c0 + lc;
        v0 = ((const bf16x8*)src)[0];
        v1 = ((const bf16x8*)src)[1];
    }
    *(bf16x8*)(&t[lr][lc])     = v0;
    *(bf16x8*)(&t[lr][lc + 8]) = v1;
    __syncthreads();

    bf16 tmp[16];
#pragma unroll
    for (int k = 0; k < 16; ++k) tmp[k] = t[lc + k][lr];
    bf16* dst = out + boff + (long)(c0 + lr) * R + r0 + lc;
    *(float4*)(dst)     = *(float4*)(&tmp[0]);
    *(float4*)(dst + 8) = *(float4*)(&tmp[8]);
}

// ---------------------------------------------------------------------------
// Shared MFMA helpers: 128x128 tile, BK=64, XOR-swizzled LDS
// (LDS[row][c] = G[row][c^(row&7)], 8-elem chunks; SQ_LDS_BANK_CONFLICT==0).
// gridDim.x==8 and gridDim.y%8==0 required for the XCD swizzle.
// ---------------------------------------------------------------------------
__device__ __forceinline__ void mfma_tile(const bf16* As, const bf16* Bs,
                                          int wm, int wn, int quad, int l15,
                                          f32x4 acc[4][4]) {
#pragma unroll
    for (int kk = 0; kk < 2; ++kk) {
        bf16x8 af[4], bff[4];
        const int kc = kk * 4 + quad;
#pragma unroll
        for (int i = 0; i < 4; ++i) {
            const int m = wm * 64 + i * 16 + l15;
            af[i] = *(const bf16x8*)(As + m * 64 + (kc ^ (m & 7)) * 8);
            const int n = wn * 64 + i * 16 + l15;
            bff[i] = *(const bf16x8*)(Bs + n * 64 + (kc ^ (n & 7)) * 8);
        }
#pragma unroll
        for (int i = 0; i < 4; ++i)
#pragma unroll
            for (int j = 0; j < 4; ++j)
                acc[i][j] = __builtin_amdgcn_mfma_f32_16x16x32_bf16(
                    af[i], bff[j], acc[i][j], 0, 0, 0);
    }
}

__device__ __forceinline__ void stageAB(const bf16* a, const bf16* b, int K,
                                        bf16* Asb, bf16* Bsb, int lbase) {
#pragma unroll
    for (int r = 0; r < 4; ++r) {
        gld_lds16(a + (long)(r * 32) * K, Asb + r * 2048 + lbase);
        gld_lds16(b + (long)(r * 32) * K, Bsb + r * 2048 + lbase);
    }
}

__device__ __forceinline__ void stageB(const bf16* b, int K, bf16* Bsb, int lbase) {
#pragma unroll
    for (int r = 0; r < 4; ++r)
        gld_lds16(b + (long)(r * 32) * K, Bsb + r * 2048 + lbase);
}

__device__ __forceinline__ void issueA_f32(const char* Ag4, int K, int k0,
                                           float4 fa[8]) {
#pragma unroll
    for (int r = 0; r < 4; ++r) {
        const float4* pa = (const float4*)(Ag4 + ((long)(r * 32) * K + k0) * 4);
        fa[2 * r]     = pa[0];
        fa[2 * r + 1] = pa[1];
    }
}

__device__ __forceinline__ void writeA_cvt(bf16* Asb, const float4 fa[8], int ldst) {
#pragma unroll
    for (int r = 0; r < 4; ++r) {
        const float4 f0 = fa[2 * r], f1 = fa[2 * r + 1];
        bf16x8 v;
        v[0]=(bf16)f0.x; v[1]=(bf16)f0.y; v[2]=(bf16)f0.z; v[3]=(bf16)f0.w;
        v[4]=(bf16)f1.x; v[5]=(bf16)f1.y; v[6]=(bf16)f1.z; v[7]=(bf16)f1.w;
        *(bf16x8*)(Asb + r * 2048 + ldst) = v;
    }
}

// bf16 K-loop: double-buffered LDS, both operands via global_load_lds,
// counted vmcnt(8) (validated on expert z=0-3, r2/r3).
__device__ __forceinline__ void kloop_bf16(const bf16* Agb, const bf16* Bg, int K,
                                           bf16* As, bf16* Bs, int lbase,
                                           int wm, int wn, int quad, int l15,
                                           f32x4 acc[4][4]) {
    const int nt = K >> 6;
    stageAB(Agb, Bg, K, As, Bs, lbase);
    for (int t = 0; t < nt; ++t) {
        const int cur = (t & 1) * 8192;
        if (t + 1 < nt) {
            const int nxt = ((t + 1) & 1) * 8192;
            stageAB(Agb + ((t + 1) << 6), Bg + ((t + 1) << 6), K,
                    As + nxt, Bs + nxt, lbase);
            asm volatile("s_waitcnt vmcnt(8)" ::: "memory");
        } else {
            asm volatile("s_waitcnt vmcnt(0)" ::: "memory");
        }
        __builtin_amdgcn_s_barrier();
        __builtin_amdgcn_sched_barrier(0);
        mfma_tile(As + cur, Bs + cur, wm, wn, quad, l15, acc);
        __builtin_amdgcn_sched_barrier(0);
        __builtin_amdgcn_s_barrier();
    }
}

// ---------------------------------------------------------------------------
// Front GEMM: C = bf16(relu(A @ Bt^T + bias)). A (M,K): if dt&&useCast, read
// bf16 from Ac (pre-cast ws); if dt&&!useCast, fp32 reg-stage fallback; if
// !dt, A_ is bf16. Bt (N,K) bf16 (ws); C bf16 (ws). grid (8, M/128).
// ---------------------------------------------------------------------------
__global__ __launch_bounds__(256, 2) void gemm_front(const void* __restrict__ A_,
                                                     const bf16* __restrict__ Ac,
                                                     const bf16* __restrict__ Bt,
                                                     const void* __restrict__ bias_,
                                                     bf16* __restrict__ C,
                                                     const int* __restrict__ flag,
                                                     int useCast,
                                                     int M, int N, int K) {
    __shared__ __align__(16) bf16 As[2][128 * 64];
    __shared__ __align__(16) bf16 Bs[2][128 * 64];

    const int dt = *flag;
    const int tid = threadIdx.x, lane = tid & 63, wid = tid >> 6;
    const int wm = wid & 1, wn = wid >> 1;

    const int lin = blockIdx.y * 8 + blockIdx.x;
    const int m0 = ((lin >> 6) * 8 + (lin & 7)) * 128;
    const int n0 = ((lin >> 3) & 7) * 128;

    const int srow = wid * 8 + (lane >> 3);
    const int scol = ((lane & 7) ^ (srow & 7)) * 8;
    const bf16* Bg = Bt + (long)(n0 + srow) * K + scol;
    const int ldst = wid * 512 + lane * 8;
    const int lbase = wid * 512;

    f32x4 acc[4][4];
#pragma unroll
    for (int i = 0; i < 4; ++i)
#pragma unroll
        for (int j = 0; j < 4; ++j) acc[i][j] = (f32x4){0.f, 0.f, 0.f, 0.f};

    const int quad = lane >> 4, l15 = lane & 15;
    const int nt = K >> 6;

    if (dt && !useCast) {  // fp32 A fallback: reg-stage (issue-early/cvt-late)
        const char* Ag4 = (const char*)A_ + ((long)(m0 + srow) * K + scol) * 4;
        float4 fa[8];
        issueA_f32(Ag4, K, 0, fa);
        stageB(Bg, K, Bs[0], lbase);
        writeA_cvt(As[0], fa, ldst);
        __syncthreads();
        int t = 0;
        for (; t < nt - 2; t += 2) {
            issueA_f32(Ag4, K, (t + 1) << 6, fa);
            stageB(Bg + ((t + 1) << 6), K, Bs[1], lbase);
            mfma_tile(As[0], Bs[0], wm, wn, quad, l15, acc);
            writeA_cvt(As[1], fa, ldst);
            __syncthreads();
            issueA_f32(Ag4, K, (t + 2) << 6, fa);
            stageB(Bg + ((t + 2) << 6), K, Bs[0], lbase);
            mfma_tile(As[1], Bs[1], wm, wn, quad, l15, acc);
            writeA_cvt(As[0], fa, ldst);
            __syncthreads();
        }
        issueA_f32(Ag4, K, (nt - 1) << 6, fa);
        stageB(Bg + ((nt - 1) << 6), K, Bs[1], lbase);
        mfma_tile(As[0], Bs[0], wm, wn, quad, l15, acc);
        writeA_cvt(As[1], fa, ldst);
        __syncthreads();
        mfma_tile(As[1], Bs[1], wm, wn, quad, l15, acc);
    } else {   // bf16 A (input or pre-cast): full gld_lds pipeline
        const bf16* Abase = dt ? Ac : (const bf16*)A_;
        const bf16* Agb = Abase + (long)(m0 + srow) * K + scol;
        kloop_bf16(Agb, Bg, K, As[0], Bs[0], lbase, wm, wn, quad, l15, acc);
    }

#pragma unroll
    for (int j = 0; j < 4; ++j) {
        const int colg = n0 + wn * 64 + j * 16 + l15;
        const float bj = dt ? ((const float*)bias_)[colg]
                            : (float)((const bf16*)bias_)[colg];
#pragma unroll
        for (int i = 0; i < 4; ++i) {
            const int rowb = m0 + wm * 64 + i * 16 + quad * 4;
#pragma unroll
            for (int r = 0; r < 4; ++r) {
                float v = acc[i][j][r] + bj;
                v = v > 0.f ? v : 0.f;
                C[(long)(rowb + r) * N + colg] = (bf16)v;
            }
        }
    }
}

// ---------------------------------------------------------------------------
// Combined expert GEMM: all 7 (group,expert) pairs in one launch. M=2048,
// N=1024; K and A vary per z. Fused layer-2 epilogue:
// atomicAdd S[m][o] += sum_n relu(acc+bias[n]) * W2[n][o].
// ---------------------------------------------------------------------------
struct ExpDescs {
    const void* A[7];
    const bf16* Ac[7];    // pre-cast bf16 A (rnn slices, dt==1)
    const bf16* Bt[7];
    const void* biasB[7];
    const void* w2B[7];
    float* S[7];
    long biasEoff[7];
    long w2Eoff[7];
    int K[7];
    int adt[7];   // 1: A has input dtype (per flag); 0: A is ws bf16
    int usec[7];  // 1: Ac valid when dt==1
};

__global__ __launch_bounds__(256, 2) void gemm_expert(ExpDescs d,
                                                      const int* __restrict__ flag) {
    __shared__ __align__(16) bf16 As[2][128 * 64];
    __shared__ __align__(16) bf16 Bs[2][128 * 64];

    const int z = blockIdx.z;
    const int dt = *flag;
    const int adt = d.adt[z];
    const int K = d.K[z];
    const void* A_ = d.A[z];
    const bf16* Bt = d.Bt[z];

    const int tid = threadIdx.x, lane = tid & 63, wid = tid >> 6;
    const int wm = wid & 1, wn = wid >> 1;

    const int lin = blockIdx.y * 8 + blockIdx.x;
    const int m0 = ((lin >> 6) * 8 + (lin & 7)) * 128;
    const int n0 = ((lin >> 3) & 7) * 128;

    const int srow = wid * 8 + (lane >> 3);
    const int scol = ((lane & 7) ^ (srow & 7)) * 8;
    const bf16* Bg = Bt + (long)(n0 + srow) * K + scol;
    const int ldst = wid * 512 + lane * 8;
    const int lbase = wid * 512;

    f32x4 acc[4][4];
#pragma unroll
    for (int i = 0; i < 4; ++i)
#pragma unroll
        for (int j = 0; j < 4; ++j) acc[i][j] = (f32x4){0.f, 0.f, 0.f, 0.f};

    const int quad = lane >> 4, l15 = lane & 15;
    const int nt = K >> 6;

    if (adt && dt && !d.usec[z]) {  // fp32 A fallback
        const char* Ag4 = (const char*)A_ + ((long)(m0 + srow) * K + scol) * 4;
        float4 fa[8];
        issueA_f32(Ag4, K, 0, fa);
        stageB(Bg, K, Bs[0], lbase);
        writeA_cvt(As[0], fa, ldst);
        __syncthreads();
        int t = 0;
        for (; t < nt - 2; t += 2) {
            issueA_f32(Ag4, K, (t + 1) << 6, fa);
            stageB(Bg + ((t + 1) << 6), K, Bs[1], lbase);
            mfma_tile(As[0], Bs[0], wm, wn, quad, l15, acc);
            writeA_cvt(As[1], fa, ldst);
            __syncthreads();
            issueA_f32(Ag4, K, (t + 2) << 6, fa);
            stageB(Bg + ((t + 2) << 6), K, Bs[0], lbase);
            mfma_tile(As[1], Bs[1], wm, wn, quad, l15, acc);
            writeA_cvt(As[0], fa, ldst);
            __syncthreads();
        }
        issueA_f32(Ag4, K, (nt - 1) << 6, fa);
        stageB(Bg + ((nt - 1) << 6), K, Bs[1], lbase);
        mfma_tile(As[0], Bs[0], wm, wn, quad, l15, acc);
        writeA_cvt(As[1], fa, ldst);
        __syncthreads();
        mfma_tile(As[1], Bs[1], wm, wn, quad, l15, acc);
    } else {    // bf16 A (ws, input, or pre-cast)
        const bf16* Abase = (adt && dt) ? d.Ac[z] : (const bf16*)A_;
        const bf16* Agb = Abase + (long)(m0 + srow) * K + scol;
        kloop_bf16(Agb, Bg, K, As[0], Bs[0], lbase, wm, wn, quad, l15, acc);
    }

    // fused layer-2 epilogue
    const long besz = dt ? 4 : 2;
    const char* bias_b = (const char*)d.biasB[z] + d.biasEoff[z] * besz;
    const char* w2_b   = (const char*)d.w2B[z] + d.w2Eoff[z] * besz;
    float* S = d.S[z];

    float bj[4], w2f[4][2];
#pragma unroll
    for (int j = 0; j < 4; ++j) {
        const int colg = n0 + wn * 64 + j * 16 + l15;
        if (dt) {
            bj[j] = ((const float*)bias_b)[colg];
            w2f[j][0] = ((const float*)w2_b)[colg * 2 + 0];
            w2f[j][1] = ((const float*)w2_b)[colg * 2 + 1];
        } else {
            bj[j] = (float)((const bf16*)bias_b)[colg];
            w2f[j][0] = (float)((const bf16*)w2_b)[colg * 2 + 0];
            w2f[j][1] = (float)((const bf16*)w2_b)[colg * 2 + 1];
        }
    }
#pragma unroll
    for (int i = 0; i < 4; ++i) {
#pragma unroll
        for (int r = 0; r < 4; ++r) {
            float s0 = 0.f, s1 = 0.f;
#pragma unroll
            for (int j = 0; j < 4; ++j) {
                float h = acc[i][j][r] + bj[j];
                h = h > 0.f ? h : 0.f;
                s0 += h * w2f[j][0];
                s1 += h * w2f[j][1];
            }
#pragma unroll
            for (int msk = 1; msk < 16; msk <<= 1) {
                s0 += __shfl_xor(s0, msk);
                s1 += __shfl_xor(s1, msk);
            }
            if (l15 == 0) {
                const int rowg = m0 + wm * 64 + i * 16 + quad * 4 + r;
                atomicAdd(&S[rowg * 2 + 0], s0);
                atomicAdd(&S[rowg * 2 + 1], s1);
            }
        }
    }
}

// ---------------------------------------------------------------------------
// x_dist[n,0:1024] = hd[3n]*hd[3n+1]; x_dist[n,1024:2048] = hd[3n+1]*hd[3n+2]
// ---------------------------------------------------------------------------
__global__ __launch_bounds__(256) void pairprod_k(const bf16* __restrict__ hd,
                                                  bf16* __restrict__ xd) {
    const int idx = blockIdx.x * 256 + threadIdx.x;  // 524288 total
    const int n = idx >> 8;
    const int c8 = (idx & 255) << 3;
    const bf16* p;
    if (c8 < 1024) p = hd + (long)(3 * n) * 1024 + c8;
    else           p = hd + (long)(3 * n + 1) * 1024 + (c8 - 1024);
    const bf16* q = p + 1024;
    bf16x8 a = *(const bf16x8*)p, b = *(const bf16x8*)q;
    bf16x8 o;
#pragma unroll
    for (int k = 0; k < 8; ++k) o[k] = (bf16)((float)a[k] * (float)b[k]);
    *(bf16x8*)(xd + (long)n * 2048 + c8) = o;
}

// ---------------------------------------------------------------------------
// out[(g*2048+n)*2+o] = S[g][eid][n][o] + b2[g][eid][o], dtype per flag.
// ---------------------------------------------------------------------------
__global__ __launch_bounds__(256) void finalize_k(const float* __restrict__ S,
        const int* __restrict__ rnn_eid, const int* __restrict__ room_eid,
        const int* __restrict__ dist_eid, const void* __restrict__ b2_rnn,
        const void* __restrict__ b2_room, const void* __restrict__ b2_dist,
        const int* __restrict__ flag, void* __restrict__ out) {
    const int idx = blockIdx.x * 256 + threadIdx.x;
    if (idx >= 12288) return;
    const int dt = *flag;
    const int o = idx & 1;
    const int row = idx >> 1;
    const int g = row >> 11;
    const int n = row & 2047;
    float v;
    if (g == 0) {
        int e = rnn_eid[n]; e = e < 0 ? 0 : (e > 2 ? 2 : e);
        v = S[e * 4096 + n * 2 + o] +
            (dt ? ((const float*)b2_rnn)[e * 2 + o]
                : (float)((const bf16*)b2_rnn)[e * 2 + o]);
    } else if (g == 1) {
        int e = room_eid[n]; e = e < 0 ? 0 : (e > 1 ? 1 : e);
        v = S[12288 + e * 4096 + n * 2 + o] +
            (dt ? ((const float*)b2_room)[e * 2 + o]
                : (float)((const bf16*)b2_room)[e * 2 + o]);
    } else {
        int e = dist_eid[n]; e = e < 0 ? 0 : (e > 1 ? 1 : e);
        v = S[20480 + e * 4096 + n * 2 + o] +
            (dt ? ((const float*)b2_dist)[e * 2 + o]
                : (float)((const bf16*)b2_dist)[e * 2 + o]);
    }
    if (dt) ((float*)out)[idx] = v;
    else    ((bf16*)out)[idx] = (bf16)v;
}

extern "C" void kernel_launch(void* const* d_in, const int* in_sizes, int n_in,
                              void* d_out, int out_size, void* d_ws, size_t ws_size,
                              hipStream_t stream) {
    const void* rnn_feats = d_in[0];
    const void* cube      = d_in[1];
    const void* ego       = d_in[2];
    const int* rnn_eid    = (const int*)d_in[3];
    const int* room_eid   = (const int*)d_in[4];
    const int* dist_eid   = (const int*)d_in[5];
    const void* Wc        = d_in[6];
    const void* bc        = d_in[7];
    const void* Wd        = d_in[8];
    const void* bd        = d_in[9];
    const void* W1_rnn    = d_in[10];
    const void* b1_rnn    = d_in[11];
    const void* W2_rnn    = d_in[12];
    const void* b2_rnn    = d_in[13];
    const void* W1_room   = d_in[14];
    const void* b1_room   = d_in[15];
    const void* W2_room   = d_in[16];
    const void* b2_room   = d_in[17];
    const void* W1_dist   = d_in[18];
    const void* b1_dist   = d_in[19];
    const void* W2_dist   = d_in[20];
    const void* b2_dist   = d_in[21];

    char* ws = (char*)d_ws;
    float* S     = (float*)ws;                    // 28672 fp32 = 114688 B
    int* flag    = (int*)(ws + 114688);           // 4 B (pad to 256)
    bf16* WcT    = (bf16*)(ws + 114944);          // 1024x3200
    bf16* WdT    = (bf16*)(ws + 6668544);         // 1024x3712
    bf16* WrnnT  = (bf16*)(ws + 14270720);        // 3x1024x1024
    bf16* WroomT = (bf16*)(ws + 20562176);        // 2x1024x8192
    bf16* WdistT = (bf16*)(ws + 54116608);        // 2x1024x2048
    bf16* hc     = (bf16*)(ws + 62505216);        // 16384x1024
    bf16* hd     = (bf16*)(ws + 96059648);        // 6144x1024
    bf16* xd     = (bf16*)(ws + 108642560);       // 2048x2048
    bf16* rnnB   = (bf16*)(ws + 117031168);       // 2048x1024 bf16 cast
    bf16* egoB   = (bf16*)(ws + 121225472);       // 6144x3712 bf16 cast
    bf16* cubeB  = (bf16*)(ws + 166838528);       // 16384x3200 bf16 cast
                                                  // end: 271696128
    const int castRnn  = ws_size >= 121225472UL ? 1 : 0;
    const int castEgo  = ws_size >= 166838528UL ? 1 : 0;
    const int castCube = ws_size >= 271696128UL ? 1 : 0;

    detect_k<<<1, 64, 0, stream>>>((const unsigned*)rnn_feats, flag);
    hipMemsetAsync(S, 0, 114688, stream);

    cast_k<<<2048, 256, 0, stream>>>((const float*)cube, (const float*)ego,
                                     (const float*)rnn_feats, cubeB, egoB, rnnB,
                                     castCube, castEgo, castRnn, flag);

    transpose_k<<<dim3(16, 50, 1),  256, 0, stream>>>(Wc,      WcT,    flag, 3200, 1024);
    transpose_k<<<dim3(16, 58, 1),  256, 0, stream>>>(Wd,      WdT,    flag, 3712, 1024);
    transpose_k<<<dim3(16, 16, 3),  256, 0, stream>>>(W1_rnn,  WrnnT,  flag, 1024, 1024);
    transpose_k<<<dim3(16, 128, 2), 256, 0, stream>>>(W1_room, WroomT, flag, 8192, 1024);
    transpose_k<<<dim3(16, 32, 2),  256, 0, stream>>>(W1_dist, WdistT, flag, 2048, 1024);

    // hc = relu(cube @ Wc + bc) (16384x1024); hd = relu(ego @ Wd + bd) (6144x1024)
    gemm_front<<<dim3(8, 128), 256, 0, stream>>>(cube, cubeB, WcT, bc, hc, flag,
                                                 castCube, 16384, 1024, 3200);
    gemm_front<<<dim3(8, 48), 256, 0, stream>>>(ego, egoB, WdT, bd, hd, flag,
                                                castEgo, 6144, 1024, 3712);
    pairprod_k<<<2048, 256, 0, stream>>>(hd, xd);

    // all 7 expert GEMMs (layer1 + fused layer2 -> S); room (K=8192) first.
    ExpDescs D;
    for (int e = 0; e < 2; ++e) {
        const int z = e;
        D.A[z] = hc;                   D.Ac[z] = nullptr;
        D.Bt[z] = WroomT + (long)e * 1024 * 8192;
        D.biasB[z] = b1_room;          D.biasEoff[z] = (long)e * 1024;
        D.w2B[z] = W2_room;            D.w2Eoff[z] = (long)e * 2048;
        D.S[z] = S + 12288 + e * 4096; D.K[z] = 8192;
        D.adt[z] = 0;                  D.usec[z] = 0;
    }
    for (int e = 0; e < 2; ++e) {
        const int z = 2 + e;
        D.A[z] = xd;                   D.Ac[z] = nullptr;
        D.Bt[z] = WdistT + (long)e * 1024 * 2048;
        D.biasB[z] = b1_dist;          D.biasEoff[z] = (long)e * 1024;
        D.w2B[z] = W2_dist;            D.w2Eoff[z] = (long)e * 2048;
        D.S[z] = S + 20480 + e * 4096; D.K[z] = 2048;
        D.adt[z] = 0;                  D.usec[z] = 0;
    }
    for (int e = 0; e < 3; ++e) {
        const int z = 4 + e;
        D.A[z] = rnn_feats;            D.Ac[z] = rnnB;
        D.Bt[z] = WrnnT + (long)e * 1024 * 1024;
        D.biasB[z] = b1_rnn;           D.biasEoff[z] = (long)e * 1024;
        D.w2B[z] = W2_rnn;             D.w2Eoff[z] = (long)e * 2048;
        D.S[z] = S + e * 4096;         D.K[z] = 1024;
        D.adt[z] = 1;                  D.usec[z] = castRnn;
    }
    gemm_expert<<<dim3(8, 16, 7), 256, 0, stream>>>(D, flag);

    finalize_k<<<48, 256, 0, stream>>>(S, rnn_eid, room_eid, dist_eid,
                                       b2_rnn, b2_room, b2_dist, flag, d_out);
}

// Round 5
// 838.371 us; speedup vs baseline: 1.1427x; 1.0686x over previous
//
#include <hip/hip_runtime.h>

typedef __bf16 bf16;
typedef __bf16 bf16x8 __attribute__((ext_vector_type(8)));
typedef float f32x4 __attribute__((ext_vector_type(4)));

__device__ __forceinline__ void gld_lds16(const bf16* g, bf16* lds_base) {
    __builtin_amdgcn_global_load_lds(
        (const __attribute__((address_space(1))) void*)g,
        (__attribute__((address_space(3))) void*)lds_base, 16, 0, 0);
}

#define MFMA16(a, b, c) __builtin_amdgcn_mfma_f32_16x16x32_bf16((a), (b), (c), 0, 0, 0)

// ---------------------------------------------------------------------------
// Dtype detector: flag=0 if float tensors are bf16, 1 if fp32.
// (Measured: flag==1 on this bench -- inputs are fp32.)
// ---------------------------------------------------------------------------
__global__ void detect_k(const unsigned* __restrict__ rnn, int* __restrict__ flag) {
    const int lane = threadIdx.x;  // 64 threads
    const unsigned w = rnn[lane];
    const int e = (w >> 7) & 0xFF;
    const bool good = (e >= 100 && e <= 130);
    const unsigned long long m = __ballot(good);
    if (lane == 0) *flag = (__popcll(m) >= 48) ? 0 : 1;
}

// ---------------------------------------------------------------------------
// S-zero + fp32->bf16 cast of activation tensors (cast only when dt==1).
// ---------------------------------------------------------------------------
__device__ __forceinline__ void cvt8(const float* __restrict__ s,
                                     bf16* __restrict__ d, long i8) {
    const float4* p = (const float4*)(s + i8 * 8);
    const float4 f0 = p[0], f1 = p[1];
    bf16x8 v;
    v[0]=(bf16)f0.x; v[1]=(bf16)f0.y; v[2]=(bf16)f0.z; v[3]=(bf16)f0.w;
    v[4]=(bf16)f1.x; v[5]=(bf16)f1.y; v[6]=(bf16)f1.z; v[7]=(bf16)f1.w;
    *(bf16x8*)(d + i8 * 8) = v;
}

__global__ __launch_bounds__(256) void cast_k(
        const float* __restrict__ cube, const float* __restrict__ ego,
        const float* __restrict__ rnn, bf16* __restrict__ cubeB,
        bf16* __restrict__ egoB, bf16* __restrict__ rnnB,
        float* __restrict__ S,
        int cc, int ce, int cr, const int* __restrict__ flag) {
    const long tid = (long)blockIdx.x * 256 + threadIdx.x;
    const long stride = (long)gridDim.x * 256;
    for (long i = tid; i < 28672; i += stride) S[i] = 0.f;   // zero accumulators
    if (*flag == 0) return;   // inputs already bf16
    if (cc) for (long i = tid; i < 6553600; i += stride) cvt8(cube, cubeB, i);
    if (ce) for (long i = tid; i < 2850816; i += stride) cvt8(ego, egoB, i);
    if (cr) for (long i = tid; i < 262144;  i += stride) cvt8(rnn, rnnB, i);
}

// ---------------------------------------------------------------------------
// All 5 weight transposes in ONE launch. in (B,R,1024) [dtype per flag] ->
// out (B,1024,R) bf16. 64x64 tiles, 16 col-blocks per matrix (C==1024 all).
// Segment table: Wc(50,1) Wd(58,1) W1_rnn(16,3) W1_room(128,2) W1_dist(32,2).
// ---------------------------------------------------------------------------
struct TrAll {
    const void* in[5];
    bf16* out[5];
};

__global__ __launch_bounds__(256) void transpose_all_k(TrAll p,
                                                       const int* __restrict__ flag) {
    __shared__ __align__(16) bf16 t[64][72];
    const int dt = *flag;

    // segment lookup (constant offsets: 800, 928, 768, 4096, 1024 blocks)
    int bid = blockIdx.x, seg, Y;
    if      (bid < 800)  { seg = 0; Y = 50; }
    else if (bid < 1728) { seg = 1; Y = 58;  bid -= 800; }
    else if (bid < 2496) { seg = 2; Y = 16;  bid -= 1728; }
    else if (bid < 6592) { seg = 3; Y = 128; bid -= 2496; }
    else                 { seg = 4; Y = 32;  bid -= 6592; }
    const int bx = bid & 15, rest = bid >> 4;
    const int by = rest % Y, bz = rest / Y;
    const int R = Y * 64, C = 1024;

    const long boff = (long)bz * R * C;
    const int c0 = bx * 64, r0 = by * 64;
    const int lr = threadIdx.x >> 2;
    const int lc = (threadIdx.x & 3) * 16;

    bf16x8 v0, v1;
    if (dt) {
        const float* src = (const float*)p.in[seg] + boff + (long)(r0 + lr) * C + c0 + lc;
        float4 f0 = ((const float4*)src)[0];
        float4 f1 = ((const float4*)src)[1];
        float4 f2 = ((const float4*)src)[2];
        float4 f3 = ((const float4*)src)[3];
        v0[0]=(bf16)f0.x; v0[1]=(bf16)f0.y; v0[2]=(bf16)f0.z; v0[3]=(bf16)f0.w;
        v0[4]=(bf16)f1.x; v0[5]=(bf16)f1.y; v0[6]=(bf16)f1.z; v0[7]=(bf16)f1.w;
        v1[0]=(bf16)f2.x; v1[1]=(bf16)f2.y; v1[2]=(bf16)f2.z; v1[3]=(bf16)f2.w;
        v1[4]=(bf16)f3.x; v1[5]=(bf16)f3.y; v1[6]=(bf16)f3.z; v1[7]=(bf16)f3.w;
    } else {
        const bf16* src = (const bf16*)p.in[seg] + boff + (long)(r0 + lr) * C + c0 + lc;
        v0 = ((const bf16x8*)src)[0];
        v1 = ((const bf16x8*)src)[1];
    }
    *(bf16x8*)(&t[lr][lc])     = v0;
    *(bf16x8*)(&t[lr][lc + 8]) = v1;
    __syncthreads();

    bf16 tmp[16];
#pragma unroll
    for (int k = 0; k < 16; ++k) tmp[k] = t[lc + k][lr];
    bf16* dst = p.out[seg] + boff + (long)(c0 + lr) * R + r0 + lc;
    *(float4*)(dst)     = *(float4*)(&tmp[0]);
    *(float4*)(dst + 8) = *(float4*)(&tmp[8]);
}

// ===========================================================================
// 256x256 8-wave 4-phase-per-K-tile GEMM core (bf16 operands).
// BK=64, 512 threads, waves 2(M)x4(N). LDS 128 KiB: A/B each
// 2buf x 2half x [128 rows][64 k] bf16, XOR-swizzled 8-elem chunks
// (LDS[r][c8] = G[r][c8^(r&7)]; source pre-swizzled; linear gld_lds dst).
//
// Per K-tile t (quadrants m0n0,m0n1,m1n0,m1n1; B frags persist in regs so
// half-buffer last-reads are A0,B0@p1, B1@p2, A1@p3):
//   p1: ds_read A0(8)+B0(4); stage Ah1[t+1],Bh1[t+1]; bar; lgkm0; 16 MFMA; bar
//   p2: ds_read B1(4);       stage Ah0[t+2];          bar; lgkm0; 16 MFMA; bar
//   p3: ds_read A1(8);                                bar; lgkm0; 16 MFMA; bar
//   p4: stage Bh0[t+2]; 16 MFMA; vmcnt(4); bar
// vmcnt(4) audit: outstanding at p4 = {Ah0[t+1],Bh0[t+1] (from t-1), Ah1,Bh1
// [t+1] (p1), Ah0[t+2] (p2), Bh0[t+2] (p4)} = 12; waiting to 4 retires the
// oldest 8 = ALL of tile t+1 -> published by the closing barrier. Never
// drains to 0 mid-loop (T4). Requires nt >= 2.
// ===========================================================================
__device__ __forceinline__ void kloop256(const bf16* __restrict__ A,
                                         const bf16* __restrict__ Bt,
                                         int K, int m0, int n0, bf16* L,
                                         int wid, int lane,
                                         f32x4 (&acc)[2][2][4][2]) {
    const int wm = wid >> 2, wn = wid & 3;
    const int quad = lane >> 4, l15 = lane & 15;
    const int nt = K >> 6;

    const int sr = wid * 8 + (lane >> 3);
    const int sc = ((lane & 7) ^ ((lane >> 3) & 7)) * 8;   // pre-swizzled src col
    const bf16* Ag = A + (long)(m0 + sr) * K + sc;
    const bf16* Bg = Bt + (long)(n0 + sr) * K + sc;
    const long K64 = (long)K * 64, K128 = (long)K * 128;
    bf16* const As = L;            // (buf*2+half)*8192
    bf16* const Bs = L + 32768;
    const int w512 = wid * 512;

    const int arow = (wm * 64 + l15) * 64;
    const int brow = (wn * 32 + l15) * 64;
    const int swz0 = ((0 * 4 + quad) ^ (l15 & 7)) * 8;
    const int swz1 = ((1 * 4 + quad) ^ (l15 & 7)) * 8;

    // prologue: tile0 all halves + tile1 h0 halves (12 loads/thread)
    gld_lds16(Ag,              As + w512);
    gld_lds16(Ag + K64,        As + 4096 + w512);
    gld_lds16(Bg,              Bs + w512);
    gld_lds16(Bg + K64,        Bs + 4096 + w512);
    gld_lds16(Ag + K128,       As + 8192 + w512);
    gld_lds16(Ag + K128 + K64, As + 8192 + 4096 + w512);
    gld_lds16(Bg + K128,       Bs + 8192 + w512);
    gld_lds16(Bg + K128 + K64, Bs + 8192 + 4096 + w512);
    gld_lds16(Ag + 64,         As + 16384 + w512);
    gld_lds16(Ag + K64 + 64,   As + 16384 + 4096 + w512);
    gld_lds16(Bg + 64,         Bs + 16384 + w512);
    gld_lds16(Bg + K64 + 64,   Bs + 16384 + 4096 + w512);
    asm volatile("s_waitcnt vmcnt(4)" ::: "memory");   // tile0 landed
    __builtin_amdgcn_s_barrier();
    __builtin_amdgcn_sched_barrier(0);

    bf16x8 af[4][2], b0[2][2], b1[2][2];

    for (int t = 0; t < nt; ++t) {
        const int buf = t & 1, nbuf = buf ^ 1;
        bf16* A0 = As + (buf * 2 + 0) * 8192;
        bf16* A1 = As + (buf * 2 + 1) * 8192;
        bf16* B0 = Bs + (buf * 2 + 0) * 8192;
        bf16* B1 = Bs + (buf * 2 + 1) * 8192;
        const long ko1 = (long)(t + 1) * 64;
        const long ko2 = (long)(t + 2) * 64;

        // ---- phase 1: Q(m0,n0); stage Ah1[t+1], Bh1[t+1]
#pragma unroll
        for (int m = 0; m < 4; ++m) {
            af[m][0] = *(const bf16x8*)(A0 + arow + m * 1024 + swz0);
            af[m][1] = *(const bf16x8*)(A0 + arow + m * 1024 + swz1);
        }
#pragma unroll
        for (int n = 0; n < 2; ++n) {
            b0[n][0] = *(const bf16x8*)(B0 + brow + n * 1024 + swz0);
            b0[n][1] = *(const bf16x8*)(B0 + brow + n * 1024 + swz1);
        }
        if (t + 1 < nt) {
            gld_lds16(Ag + K128 + ko1,       As + (nbuf * 2 + 1) * 8192 + w512);
            gld_lds16(Ag + K128 + K64 + ko1, As + (nbuf * 2 + 1) * 8192 + 4096 + w512);
            gld_lds16(Bg + K128 + ko1,       Bs + (nbuf * 2 + 1) * 8192 + w512);
            gld_lds16(Bg + K128 + K64 + ko1, Bs + (nbuf * 2 + 1) * 8192 + 4096 + w512);
        }
        __builtin_amdgcn_s_barrier();
        asm volatile("s_waitcnt lgkmcnt(0)" ::: "memory");
        __builtin_amdgcn_sched_barrier(0);
        __builtin_amdgcn_s_setprio(1);
#pragma unroll
        for (int m = 0; m < 4; ++m)
#pragma unroll
            for (int n = 0; n < 2; ++n) {
                acc[0][0][m][n] = MFMA16(af[m][0], b0[n][0], acc[0][0][m][n]);
                acc[0][0][m][n] = MFMA16(af[m][1], b0[n][1], acc[0][0][m][n]);
            }
        __builtin_amdgcn_s_setprio(0);
        __builtin_amdgcn_sched_barrier(0);
        __builtin_amdgcn_s_barrier();
        __builtin_amdgcn_sched_barrier(0);

        // ---- phase 2: Q(m0,n1); stage Ah0[t+2]
#pragma unroll
        for (int n = 0; n < 2; ++n) {
            b1[n][0] = *(const bf16x8*)(B1 + brow + n * 1024 + swz0);
            b1[n][1] = *(const bf16x8*)(B1 + brow + n * 1024 + swz1);
        }
        if (t + 2 < nt) {
            gld_lds16(Ag + ko2,       A0 + w512);
            gld_lds16(Ag + K64 + ko2, A0 + 4096 + w512);
        }
        __builtin_amdgcn_s_barrier();
        asm volatile("s_waitcnt lgkmcnt(0)" ::: "memory");
        __builtin_amdgcn_sched_barrier(0);
        __builtin_amdgcn_s_setprio(1);
#pragma unroll
        for (int m = 0; m < 4; ++m)
#pragma unroll
            for (int n = 0; n < 2; ++n) {
                acc[0][1][m][n] = MFMA16(af[m][0], b1[n][0], acc[0][1][m][n]);
                acc[0][1][m][n] = MFMA16(af[m][1], b1[n][1], acc[0][1][m][n]);
            }
        __builtin_amdgcn_s_setprio(0);
        __builtin_amdgcn_sched_barrier(0);
        __builtin_amdgcn_s_barrier();
        __builtin_amdgcn_sched_barrier(0);

        // ---- phase 3: Q(m1,n0); no stage
#pragma unroll
        for (int m = 0; m < 4; ++m) {
            af[m][0] = *(const bf16x8*)(A1 + arow + m * 1024 + swz0);
            af[m][1] = *(const bf16x8*)(A1 + arow + m * 1024 + swz1);
        }
        __builtin_amdgcn_s_barrier();
        asm volatile("s_waitcnt lgkmcnt(0)" ::: "memory");
        __builtin_amdgcn_sched_barrier(0);
        __builtin_amdgcn_s_setprio(1);
#pragma unroll
        for (int m = 0; m < 4; ++m)
#pragma unroll
            for (int n = 0; n < 2; ++n) {
                acc[1][0][m][n] = MFMA16(af[m][0], b0[n][0], acc[1][0][m][n]);
                acc[1][0][m][n] = MFMA16(af[m][1], b0[n][1], acc[1][0][m][n]);
            }
        __builtin_amdgcn_s_setprio(0);
        __builtin_amdgcn_sched_barrier(0);
        __builtin_amdgcn_s_barrier();
        __builtin_amdgcn_sched_barrier(0);

        // ---- phase 4: Q(m1,n1); stage Bh0[t+2]; counted vmcnt; publish
        if (t + 2 < nt) {
            gld_lds16(Bg + ko2,       B0 + w512);
            gld_lds16(Bg + K64 + ko2, B0 + 4096 + w512);
        }
        __builtin_amdgcn_s_setprio(1);
#pragma unroll
        for (int m = 0; m < 4; ++m)
#pragma unroll
            for (int n = 0; n < 2; ++n) {
                acc[1][1][m][n] = MFMA16(af[m][0], b1[n][0], acc[1][1][m][n]);
                acc[1][1][m][n] = MFMA16(af[m][1], b1[n][1], acc[1][1][m][n]);
            }
        __builtin_amdgcn_s_setprio(0);
        __builtin_amdgcn_sched_barrier(0);
        if (t + 2 < nt) {
            asm volatile("s_waitcnt vmcnt(4)" ::: "memory");
        } else if (t + 1 < nt) {
            asm volatile("s_waitcnt vmcnt(0)" ::: "memory");
        }
        __builtin_amdgcn_s_barrier();
        __builtin_amdgcn_sched_barrier(0);
    }
}

// ---------------------------------------------------------------------------
// Combined 256^2 front GEMM: by<32 -> hc = relu(cube@WcT^T+bc) (16384x1024,
// K=3200); by>=32 -> hd = relu(ego@WdT^T+bd) (6144x1024, K=3712).
// grid (8,44), 512 threads, 1 block/CU (128 KiB LDS). A is pre-cast bf16
// when dt==1, or the original bf16 input when dt==0.
// ---------------------------------------------------------------------------
__global__ __launch_bounds__(512, 2) void front256_k(
        const void* __restrict__ cubeIn, const bf16* __restrict__ cubeB,
        const bf16* __restrict__ WcT, const void* __restrict__ bc,
        bf16* __restrict__ hc,
        const void* __restrict__ egoIn, const bf16* __restrict__ egoB,
        const bf16* __restrict__ WdT, const void* __restrict__ bd,
        bf16* __restrict__ hd,
        const int* __restrict__ flag) {
    __shared__ __align__(16) bf16 L[65536];
    const int dt = *flag;
    const int tid = threadIdx.x, lane = tid & 63, wid = tid >> 6;
    const int N = 1024;

    const bf16* A;
    const bf16* Bt;
    const void* bias_;
    bf16* C;
    int K, m0, n0;
    if (blockIdx.y < 32) {   // hc part: 256 blocks, 64 m-tiles x 4 n-tiles
        const int lin = blockIdx.y * 8 + blockIdx.x;
        const int x = lin & 7, j = lin >> 3;
        m0 = (x * 8 + (j >> 2)) * 256;
        n0 = (j & 3) * 256;
        A = dt ? cubeB : (const bf16*)cubeIn;
        Bt = WcT; bias_ = bc; C = hc; K = 3200;
    } else {                 // hd part: 96 blocks, 24 m-tiles x 4 n-tiles
        const int lin = (blockIdx.y - 32) * 8 + blockIdx.x;
        const int x = lin & 7, j = lin >> 3;
        m0 = (x * 3 + (j >> 2)) * 256;
        n0 = (j & 3) * 256;
        A = dt ? egoB : (const bf16*)egoIn;
        Bt = WdT; bias_ = bd; C = hd; K = 3712;
    }

    f32x4 acc[2][2][4][2];
#pragma unroll
    for (int a = 0; a < 2; ++a)
#pragma unroll
        for (int b = 0; b < 2; ++b)
#pragma unroll
            for (int m = 0; m < 4; ++m)
#pragma unroll
                for (int n = 0; n < 2; ++n) acc[a][b][m][n] = (f32x4){0.f,0.f,0.f,0.f};

    kloop256(A, Bt, K, m0, n0, L, wid, lane, acc);

    const int wm = wid >> 2, wn = wid & 3;
    const int quad = lane >> 4, l15 = lane & 15;
#pragma unroll
    for (int qn = 0; qn < 2; ++qn)
#pragma unroll
        for (int n = 0; n < 2; ++n) {
            const int colg = n0 + qn * 128 + wn * 32 + n * 16 + l15;
            const float bj = dt ? ((const float*)bias_)[colg]
                                : (float)((const bf16*)bias_)[colg];
#pragma unroll
            for (int qm = 0; qm < 2; ++qm)
#pragma unroll
                for (int m = 0; m < 4; ++m) {
                    const int rowb = m0 + qm * 128 + wm * 64 + m * 16 + quad * 4;
#pragma unroll
                    for (int r = 0; r < 4; ++r) {
                        float v = acc[qm][qn][m][n][r] + bj;
                        v = v > 0.f ? v : 0.f;
                        C[(long)(rowb + r) * N + colg] = (bf16)v;
                    }
                }
        }
}

// ===========================================================================
// 128^2 kernels (validated r1-r4): used for all experts + fp32 fallback.
// ===========================================================================
__device__ __forceinline__ void mfma_tile(const bf16* As, const bf16* Bs,
                                          int wm, int wn, int quad, int l15,
                                          f32x4 acc[4][4]) {
#pragma unroll
    for (int kk = 0; kk < 2; ++kk) {
        bf16x8 af[4], bff[4];
        const int kc = kk * 4 + quad;
#pragma unroll
        for (int i = 0; i < 4; ++i) {
            const int m = wm * 64 + i * 16 + l15;
            af[i] = *(const bf16x8*)(As + m * 64 + (kc ^ (m & 7)) * 8);
            const int n = wn * 64 + i * 16 + l15;
            bff[i] = *(const bf16x8*)(Bs + n * 64 + (kc ^ (n & 7)) * 8);
        }
#pragma unroll
        for (int i = 0; i < 4; ++i)
#pragma unroll
            for (int j = 0; j < 4; ++j)
                acc[i][j] = __builtin_amdgcn_mfma_f32_16x16x32_bf16(
                    af[i], bff[j], acc[i][j], 0, 0, 0);
    }
}

__device__ __forceinline__ void stageAB(const bf16* a, const bf16* b, int K,
                                        bf16* Asb, bf16* Bsb, int lbase) {
#pragma unroll
    for (int r = 0; r < 4; ++r) {
        gld_lds16(a + (long)(r * 32) * K, Asb + r * 2048 + lbase);
        gld_lds16(b + (long)(r * 32) * K, Bsb + r * 2048 + lbase);
    }
}

__device__ __forceinline__ void stageB(const bf16* b, int K, bf16* Bsb, int lbase) {
#pragma unroll
    for (int r = 0; r < 4; ++r)
        gld_lds16(b + (long)(r * 32) * K, Bsb + r * 2048 + lbase);
}

__device__ __forceinline__ void issueA_f32(const char* Ag4, int K, int k0,
                                           float4 fa[8]) {
#pragma unroll
    for (int r = 0; r < 4; ++r) {
        const float4* pa = (const float4*)(Ag4 + ((long)(r * 32) * K + k0) * 4);
        fa[2 * r]     = pa[0];
        fa[2 * r + 1] = pa[1];
    }
}

__device__ __forceinline__ void writeA_cvt(bf16* Asb, const float4 fa[8], int ldst) {
#pragma unroll
    for (int r = 0; r < 4; ++r) {
        const float4 f0 = fa[2 * r], f1 = fa[2 * r + 1];
        bf16x8 v;
        v[0]=(bf16)f0.x; v[1]=(bf16)f0.y; v[2]=(bf16)f0.z; v[3]=(bf16)f0.w;
        v[4]=(bf16)f1.x; v[5]=(bf16)f1.y; v[6]=(bf16)f1.z; v[7]=(bf16)f1.w;
        *(bf16x8*)(Asb + r * 2048 + ldst) = v;
    }
}

__device__ __forceinline__ void kloop_bf16(const bf16* Agb, const bf16* Bg, int K,
                                           bf16* As, bf16* Bs, int lbase,
                                           int wm, int wn, int quad, int l15,
                                           f32x4 acc[4][4]) {
    const int nt = K >> 6;
    stageAB(Agb, Bg, K, As, Bs, lbase);
    for (int t = 0; t < nt; ++t) {
        const int cur = (t & 1) * 8192;
        if (t + 1 < nt) {
            const int nxt = ((t + 1) & 1) * 8192;
            stageAB(Agb + ((t + 1) << 6), Bg + ((t + 1) << 6), K,
                    As + nxt, Bs + nxt, lbase);
            asm volatile("s_waitcnt vmcnt(8)" ::: "memory");
        } else {
            asm volatile("s_waitcnt vmcnt(0)" ::: "memory");
        }
        __builtin_amdgcn_s_barrier();
        __builtin_amdgcn_sched_barrier(0);
        mfma_tile(As + cur, Bs + cur, wm, wn, quad, l15, acc);
        __builtin_amdgcn_sched_barrier(0);
        __builtin_amdgcn_s_barrier();
    }
}

// fp32-input 128^2 front GEMM (fallback only, when ws too small to cast)
__global__ __launch_bounds__(256, 2) void gemm_front(const void* __restrict__ A_,
                                                     const bf16* __restrict__ Bt,
                                                     const void* __restrict__ bias_,
                                                     bf16* __restrict__ C,
                                                     const int* __restrict__ flag,
                                                     int M, int N, int K) {
    __shared__ __align__(16) bf16 As[2][128 * 64];
    __shared__ __align__(16) bf16 Bs[2][128 * 64];

    const int dt = *flag;
    const int tid = threadIdx.x, lane = tid & 63, wid = tid >> 6;
    const int wm = wid & 1, wn = wid >> 1;

    const int lin = blockIdx.y * 8 + blockIdx.x;
    const int m0 = ((lin >> 6) * 8 + (lin & 7)) * 128;
    const int n0 = ((lin >> 3) & 7) * 128;

    const int srow = wid * 8 + (lane >> 3);
    const int scol = ((lane & 7) ^ (srow & 7)) * 8;
    const bf16* Bg = Bt + (long)(n0 + srow) * K + scol;
    const int ldst = wid * 512 + lane * 8;
    const int lbase = wid * 512;

    f32x4 acc[4][4];
#pragma unroll
    for (int i = 0; i < 4; ++i)
#pragma unroll
        for (int j = 0; j < 4; ++j) acc[i][j] = (f32x4){0.f, 0.f, 0.f, 0.f};

    const int quad = lane >> 4, l15 = lane & 15;
    const int nt = K >> 6;

    if (dt) {  // fp32 A: reg-stage (issue-early/cvt-late), async B
        const char* Ag4 = (const char*)A_ + ((long)(m0 + srow) * K + scol) * 4;
        float4 fa[8];
        issueA_f32(Ag4, K, 0, fa);
        stageB(Bg, K, Bs[0], lbase);
        writeA_cvt(As[0], fa, ldst);
        __syncthreads();
        int t = 0;
        for (; t < nt - 2; t += 2) {
            issueA_f32(Ag4, K, (t + 1) << 6, fa);
            stageB(Bg + ((t + 1) << 6), K, Bs[1], lbase);
            mfma_tile(As[0], Bs[0], wm, wn, quad, l15, acc);
            writeA_cvt(As[1], fa, ldst);
            __syncthreads();
            issueA_f32(Ag4, K, (t + 2) << 6, fa);
            stageB(Bg + ((t + 2) << 6), K, Bs[0], lbase);
            mfma_tile(As[1], Bs[1], wm, wn, quad, l15, acc);
            writeA_cvt(As[0], fa, ldst);
            __syncthreads();
        }
        issueA_f32(Ag4, K, (nt - 1) << 6, fa);
        stageB(Bg + ((nt - 1) << 6), K, Bs[1], lbase);
        mfma_tile(As[0], Bs[0], wm, wn, quad, l15, acc);
        writeA_cvt(As[1], fa, ldst);
        __syncthreads();
        mfma_tile(As[1], Bs[1], wm, wn, quad, l15, acc);
    } else {
        const bf16* Agb = (const bf16*)A_ + (long)(m0 + srow) * K + scol;
        kloop_bf16(Agb, Bg, K, As[0], Bs[0], lbase, wm, wn, quad, l15, acc);
    }

#pragma unroll
    for (int j = 0; j < 4; ++j) {
        const int colg = n0 + wn * 64 + j * 16 + l15;
        const float bj = dt ? ((const float*)bias_)[colg]
                            : (float)((const bf16*)bias_)[colg];
#pragma unroll
        for (int i = 0; i < 4; ++i) {
            const int rowb = m0 + wm * 64 + i * 16 + quad * 4;
#pragma unroll
            for (int r = 0; r < 4; ++r) {
                float v = acc[i][j][r] + bj;
                v = v > 0.f ? v : 0.f;
                C[(long)(rowb + r) * N + colg] = (bf16)v;
            }
        }
    }
}

// ---------------------------------------------------------------------------
// Combined expert GEMM (128^2): all 7 (group,expert) pairs, fused layer-2
// epilogue: atomicAdd S[m][o] += sum_n relu(acc+bias[n]) * W2[n][o].
// ---------------------------------------------------------------------------
struct ExpDescs {
    const void* A[7];
    const bf16* Ac[7];    // pre-cast bf16 A (rnn slices, dt==1)
    const bf16* Bt[7];
    const void* biasB[7];
    const void* w2B[7];
    float* S[7];
    long biasEoff[7];
    long w2Eoff[7];
    int K[7];
    int adt[7];   // 1: A has input dtype (per flag); 0: A is ws bf16
    int usec[7];  // 1: Ac valid when dt==1
};

__global__ __launch_bounds__(256, 2) void gemm_expert(ExpDescs d,
                                                      const int* __restrict__ flag) {
    __shared__ __align__(16) bf16 As[2][128 * 64];
    __shared__ __align__(16) bf16 Bs[2][128 * 64];

    const int z = blockIdx.z;
    const int dt = *flag;
    const int adt = d.adt[z];
    const int K = d.K[z];
    const void* A_ = d.A[z];
    const bf16* Bt = d.Bt[z];

    const int tid = threadIdx.x, lane = tid & 63, wid = tid >> 6;
    const int wm = wid & 1, wn = wid >> 1;

    const int lin = blockIdx.y * 8 + blockIdx.x;
    const int m0 = ((lin >> 6) * 8 + (lin & 7)) * 128;
    const int n0 = ((lin >> 3) & 7) * 128;

    const int srow = wid * 8 + (lane >> 3);
    const int scol = ((lane & 7) ^ (srow & 7)) * 8;
    const bf16* Bg = Bt + (long)(n0 + srow) * K + scol;
    const int ldst = wid * 512 + lane * 8;
    const int lbase = wid * 512;

    f32x4 acc[4][4];
#pragma unroll
    for (int i = 0; i < 4; ++i)
#pragma unroll
        for (int j = 0; j < 4; ++j) acc[i][j] = (f32x4){0.f, 0.f, 0.f, 0.f};

    const int quad = lane >> 4, l15 = lane & 15;
    const int nt = K >> 6;

    if (adt && dt && !d.usec[z]) {  // fp32 A fallback
        const char* Ag4 = (const char*)A_ + ((long)(m0 + srow) * K + scol) * 4;
        float4 fa[8];
        issueA_f32(Ag4, K, 0, fa);
        stageB(Bg, K, Bs[0], lbase);
        writeA_cvt(As[0], fa, ldst);
        __syncthreads();
        int t = 0;
        for (; t < nt - 2; t += 2) {
            issueA_f32(Ag4, K, (t + 1) << 6, fa);
            stageB(Bg + ((t + 1) << 6), K, Bs[1], lbase);
            mfma_tile(As[0], Bs[0], wm, wn, quad, l15, acc);
            writeA_cvt(As[1], fa, ldst);
            __syncthreads();
            issueA_f32(Ag4, K, (t + 2) << 6, fa);
            stageB(Bg + ((t + 2) << 6), K, Bs[0], lbase);
            mfma_tile(As[1], Bs[1], wm, wn, quad, l15, acc);
            writeA_cvt(As[0], fa, ldst);
            __syncthreads();
        }
        issueA_f32(Ag4, K, (nt - 1) << 6, fa);
        stageB(Bg + ((nt - 1) << 6), K, Bs[1], lbase);
        mfma_tile(As[0], Bs[0], wm, wn, quad, l15, acc);
        writeA_cvt(As[1], fa, ldst);
        __syncthreads();
        mfma_tile(As[1], Bs[1], wm, wn, quad, l15, acc);
    } else {    // bf16 A (ws, input, or pre-cast)
        const bf16* Abase = (adt && dt) ? d.Ac[z] : (const bf16*)A_;
        const bf16* Agb = Abase + (long)(m0 + srow) * K + scol;
        kloop_bf16(Agb, Bg, K, As[0], Bs[0], lbase, wm, wn, quad, l15, acc);
    }

    // fused layer-2 epilogue
    const long besz = dt ? 4 : 2;
    const char* bias_b = (const char*)d.biasB[z] + d.biasEoff[z] * besz;
    const char* w2_b   = (const char*)d.w2B[z] + d.w2Eoff[z] * besz;
    float* S = d.S[z];

    float bj[4], w2f[4][2];
#pragma unroll
    for (int j = 0; j < 4; ++j) {
        const int colg = n0 + wn * 64 + j * 16 + l15;
        if (dt) {
            bj[j] = ((const float*)bias_b)[colg];
            w2f[j][0] = ((const float*)w2_b)[colg * 2 + 0];
            w2f[j][1] = ((const float*)w2_b)[colg * 2 + 1];
        } else {
            bj[j] = (float)((const bf16*)bias_b)[colg];
            w2f[j][0] = (float)((const bf16*)w2_b)[colg * 2 + 0];
            w2f[j][1] = (float)((const bf16*)w2_b)[colg * 2 + 1];
        }
    }
#pragma unroll
    for (int i = 0; i < 4; ++i) {
#pragma unroll
        for (int r = 0; r < 4; ++r) {
            float s0 = 0.f, s1 = 0.f;
#pragma unroll
            for (int j = 0; j < 4; ++j) {
                float h = acc[i][j][r] + bj[j];
                h = h > 0.f ? h : 0.f;
                s0 += h * w2f[j][0];
                s1 += h * w2f[j][1];
            }
#pragma unroll
            for (int msk = 1; msk < 16; msk <<= 1) {
                s0 += __shfl_xor(s0, msk);
                s1 += __shfl_xor(s1, msk);
            }
            if (l15 == 0) {
                const int rowg = m0 + wm * 64 + i * 16 + quad * 4 + r;
                atomicAdd(&S[rowg * 2 + 0], s0);
                atomicAdd(&S[rowg * 2 + 1], s1);
            }
        }
    }
}

// ---------------------------------------------------------------------------
// x_dist[n,0:1024] = hd[3n]*hd[3n+1]; x_dist[n,1024:2048] = hd[3n+1]*hd[3n+2]
// ---------------------------------------------------------------------------
__global__ __launch_bounds__(256) void pairprod_k(const bf16* __restrict__ hd,
                                                  bf16* __restrict__ xd) {
    const int idx = blockIdx.x * 256 + threadIdx.x;  // 524288 total
    const int n = idx >> 8;
    const int c8 = (idx & 255) << 3;
    const bf16* p;
    if (c8 < 1024) p = hd + (long)(3 * n) * 1024 + c8;
    else           p = hd + (long)(3 * n + 1) * 1024 + (c8 - 1024);
    const bf16* q = p + 1024;
    bf16x8 a = *(const bf16x8*)p, b = *(const bf16x8*)q;
    bf16x8 o;
#pragma unroll
    for (int k = 0; k < 8; ++k) o[k] = (bf16)((float)a[k] * (float)b[k]);
    *(bf16x8*)(xd + (long)n * 2048 + c8) = o;
}

// ---------------------------------------------------------------------------
// out[(g*2048+n)*2+o] = S[g][eid][n][o] + b2[g][eid][o], dtype per flag.
// ---------------------------------------------------------------------------
__global__ __launch_bounds__(256) void finalize_k(const float* __restrict__ S,
        const int* __restrict__ rnn_eid, const int* __restrict__ room_eid,
        const int* __restrict__ dist_eid, const void* __restrict__ b2_rnn,
        const void* __restrict__ b2_room, const void* __restrict__ b2_dist,
        const int* __restrict__ flag, void* __restrict__ out) {
    const int idx = blockIdx.x * 256 + threadIdx.x;
    if (idx >= 12288) return;
    const int dt = *flag;
    const int o = idx & 1;
    const int row = idx >> 1;
    const int g = row >> 11;
    const int n = row & 2047;
    float v;
    if (g == 0) {
        int e = rnn_eid[n]; e = e < 0 ? 0 : (e > 2 ? 2 : e);
        v = S[e * 4096 + n * 2 + o] +
            (dt ? ((const float*)b2_rnn)[e * 2 + o]
                : (float)((const bf16*)b2_rnn)[e * 2 + o]);
    } else if (g == 1) {
        int e = room_eid[n]; e = e < 0 ? 0 : (e > 1 ? 1 : e);
        v = S[12288 + e * 4096 + n * 2 + o] +
            (dt ? ((const float*)b2_room)[e * 2 + o]
                : (float)((const bf16*)b2_room)[e * 2 + o]);
    } else {
        int e = dist_eid[n]; e = e < 0 ? 0 : (e > 1 ? 1 : e);
        v = S[20480 + e * 4096 + n * 2 + o] +
            (dt ? ((const float*)b2_dist)[e * 2 + o]
                : (float)((const bf16*)b2_dist)[e * 2 + o]);
    }
    if (dt) ((float*)out)[idx] = v;
    else    ((bf16*)out)[idx] = (bf16)v;
}

extern "C" void kernel_launch(void* const* d_in, const int* in_sizes, int n_in,
                              void* d_out, int out_size, void* d_ws, size_t ws_size,
                              hipStream_t stream) {
    const void* rnn_feats = d_in[0];
    const void* cube      = d_in[1];
    const void* ego       = d_in[2];
    const int* rnn_eid    = (const int*)d_in[3];
    const int* room_eid   = (const int*)d_in[4];
    const int* dist_eid   = (const int*)d_in[5];
    const void* Wc        = d_in[6];
    const void* bc        = d_in[7];
    const void* Wd        = d_in[8];
    const void* bd        = d_in[9];
    const void* W1_rnn    = d_in[10];
    const void* b1_rnn    = d_in[11];
    const void* W2_rnn    = d_in[12];
    const void* b2_rnn    = d_in[13];
    const void* W1_room   = d_in[14];
    const void* b1_room   = d_in[15];
    const void* W2_room   = d_in[16];
    const void* b2_room   = d_in[17];
    const void* W1_dist   = d_in[18];
    const void* b1_dist   = d_in[19];
    const void* W2_dist   = d_in[20];
    const void* b2_dist   = d_in[21];

    char* ws = (char*)d_ws;
    float* S     = (float*)ws;                    // 28672 fp32 = 114688 B
    int* flag    = (int*)(ws + 114688);           // 4 B (pad to 256)
    bf16* WcT    = (bf16*)(ws + 114944);          // 1024x3200
    bf16* WdT    = (bf16*)(ws + 6668544);         // 1024x3712
    bf16* WrnnT  = (bf16*)(ws + 14270720);        // 3x1024x1024
    bf16* WroomT = (bf16*)(ws + 20562176);        // 2x1024x8192
    bf16* WdistT = (bf16*)(ws + 54116608);        // 2x1024x2048
    bf16* hc     = (bf16*)(ws + 62505216);        // 16384x1024
    bf16* hd     = (bf16*)(ws + 96059648);        // 6144x1024
    bf16* xd     = (bf16*)(ws + 108642560);       // 2048x2048
    bf16* rnnB   = (bf16*)(ws + 117031168);       // 2048x1024 bf16 cast
    bf16* egoB   = (bf16*)(ws + 121225472);       // 6144x3712 bf16 cast
    bf16* cubeB  = (bf16*)(ws + 166838528);       // 16384x3200 bf16 cast
                                                  // end: 271696128
    const int castRnn  = ws_size >= 121225472UL ? 1 : 0;
    const int castEgo  = ws_size >= 166838528UL ? 1 : 0;
    const int castCube = ws_size >= 271696128UL ? 1 : 0;
    const int fastPath = castRnn && castEgo && castCube;

    detect_k<<<1, 64, 0, stream>>>((const unsigned*)rnn_feats, flag);

    // S-zero + activation casts in one launch
    cast_k<<<2048, 256, 0, stream>>>((const float*)cube, (const float*)ego,
                                     (const float*)rnn_feats, cubeB, egoB, rnnB,
                                     S, castCube, castEgo, castRnn, flag);

    // all 5 weight transposes in one launch (7616 blocks)
    TrAll T;
    T.in[0] = Wc;      T.out[0] = WcT;
    T.in[1] = Wd;      T.out[1] = WdT;
    T.in[2] = W1_rnn;  T.out[2] = WrnnT;
    T.in[3] = W1_room; T.out[3] = WroomT;
    T.in[4] = W1_dist; T.out[4] = WdistT;
    transpose_all_k<<<7616, 256, 0, stream>>>(T, flag);

    if (fastPath) {
        // hc (by<32) + hd (by>=32) in one 256^2 launch: 352 blocks, 1/CU
        front256_k<<<dim3(8, 44), 512, 0, stream>>>(cube, cubeB, WcT, bc, hc,
                                                    ego, egoB, WdT, bd, hd, flag);
    } else {
        gemm_front<<<dim3(8, 128), 256, 0, stream>>>(cube, WcT, bc, hc, flag,
                                                     16384, 1024, 3200);
        gemm_front<<<dim3(8, 48), 256, 0, stream>>>(ego, WdT, bd, hd, flag,
                                                    6144, 1024, 3712);
    }
    pairprod_k<<<2048, 256, 0, stream>>>(hd, xd);

    // all 7 expert GEMMs (layer1 + fused layer2 -> S); room (K=8192) first.
    ExpDescs D;
    for (int e = 0; e < 2; ++e) {
        const int z = e;
        D.A[z] = hc;                   D.Ac[z] = nullptr;
        D.Bt[z] = WroomT + (long)e * 1024 * 8192;
        D.biasB[z] = b1_room;          D.biasEoff[z] = (long)e * 1024;
        D.w2B[z] = W2_room;            D.w2Eoff[z] = (long)e * 2048;
        D.S[z] = S + 12288 + e * 4096; D.K[z] = 8192;
        D.adt[z] = 0;                  D.usec[z] = 0;
    }
    for (int e = 0; e < 2; ++e) {
        const int z = 2 + e;
        D.A[z] = xd;                   D.Ac[z] = nullptr;
        D.Bt[z] = WdistT + (long)e * 1024 * 2048;
        D.biasB[z] = b1_dist;          D.biasEoff[z] = (long)e * 1024;
        D.w2B[z] = W2_dist;            D.w2Eoff[z] = (long)e * 2048;
        D.S[z] = S + 20480 + e * 4096; D.K[z] = 2048;
        D.adt[z] = 0;                  D.usec[z] = 0;
    }
    for (int e = 0; e < 3; ++e) {
        const int z = 4 + e;
        D.A[z] = rnn_feats;            D.Ac[z] = rnnB;
        D.Bt[z] = WrnnT + (long)e * 1024 * 1024;
        D.biasB[z] = b1_rnn;           D.biasEoff[z] = (long)e * 1024;
        D.w2B[z] = W2_rnn;             D.w2Eoff[z] = (long)e * 2048;
        D.S[z] = S + e * 4096;         D.K[z] = 1024;
        D.adt[z] = 1;                  D.usec[z] = castRnn;
    }
    gemm_expert<<<dim3(8, 16, 7), 256, 0, stream>>>(D, flag);

    finalize_k<<<48, 256, 0, stream>>>(S, rnn_eid, room_eid, dist_eid,
                                       b2_rnn, b2_room, b2_dist, flag, d_out);
}